// Round 5
// baseline (568.820 us; speedup 1.0000x reference)
//
#include <hip/hip_runtime.h>

typedef unsigned short u16;
typedef unsigned int   u32;

#define N_NODES 100000
#define CHUNK_EC 2048
#define NTILES 3125   // N_NODES / 32, exact
#define GGRID  512

typedef short frag8 __attribute__((ext_vector_type(8)));
typedef float f32x4 __attribute__((ext_vector_type(4)));
typedef float f32x2 __attribute__((ext_vector_type(2)));
typedef u32   u32x4 __attribute__((ext_vector_type(4)));

template <typename T>
__device__ __forceinline__ T ntload(const T* p) { return __builtin_nontemporal_load(p); }
template <typename T>
__device__ __forceinline__ void ntstore(T v, T* p) { __builtin_nontemporal_store(v, p); }

__device__ __forceinline__ float bf2f(u16 h) {
    union { u32 u; float f; } c; c.u = ((u32)h) << 16; return c.f;
}
__device__ __forceinline__ u16 f2bf(float f) {
    union { float f; u32 u; } c; c.f = f;
    u32 u = c.u;
    return (u16)((u + 0x7FFFu + ((u >> 16) & 1u)) >> 16);
}
__device__ __forceinline__ float2 bfx2(u32 u) {
    union { u32 u; float f; } lo, hi;
    lo.u = u << 16; hi.u = u & 0xFFFF0000u;
    return make_float2(lo.f, hi.f);
}
__device__ __forceinline__ u32 packbf(float a, float b) {
    return (u32)f2bf(a) | ((u32)f2bf(b) << 16);
}
__device__ __forceinline__ void accum8(float* av, u32x4 q) {
    float2 p0 = bfx2(q[0]), p1 = bfx2(q[1]), p2 = bfx2(q[2]), p3 = bfx2(q[3]);
    av[0] += p0.x; av[1] += p0.y; av[2] += p1.x; av[3] += p1.y;
    av[4] += p2.x; av[5] += p2.y; av[6] += p3.x; av[7] += p3.y;
}

// global -> LDS direct DMA, 16B/lane, linear LDS dest (wave-uniform base + lane*16)
__device__ __forceinline__ void gload16(const void* g, void* lds) {
    __builtin_amdgcn_global_load_lds(
        (const __attribute__((address_space(1))) unsigned int*)g,
        (__attribute__((address_space(3))) unsigned int*)lds, 16, 0, 0);
}

// LDS-only barrier: orders DS ops without draining vmcnt (keeps staging in flight)
__device__ __forceinline__ void ldsbar() {
    asm volatile("s_waitcnt lgkmcnt(0)" ::: "memory");
    __builtin_amdgcn_s_barrier();
}

union U8 { frag8 f; u16 h[8]; };

// ---------------- edge-index layout detect (int32 vs int64) ----------------
__global__ void detect_kernel(const int* __restrict__ ei, int* __restrict__ flag, int E) {
    int any = 0;
    int lim = min(2048, 2 * E);
    for (int i = 1 + 2 * (int)threadIdx.x; i < lim; i += 128) any |= ei[i];
    unsigned long long b = __ballot(any != 0);
    if (threadIdx.x == 0) *flag = (b != 0ULL) ? 1 : 0;  // 1 => int32 layout
}

// ---------------- per-(block,xcd) edge counts (register counters, no atomics) ------
__global__ __launch_bounds__(256) void eccnt_kernel(const int* __restrict__ ei,
                                                    int* __restrict__ blkcnt,
                                                    const int* __restrict__ flag, int E) {
    __shared__ int lc[8];
    const int tid = threadIdx.x;
    if (tid < 8) lc[tid] = 0;
    __syncthreads();
    const int is32 = *flag;
    const int base = blockIdx.x * CHUNK_EC;
    int c[8] = {0, 0, 0, 0, 0, 0, 0, 0};
    for (int i = tid; i < CHUNK_EC; i += 256) {
        int e = base + i;
        if (e < E) {
            int d = is32 ? ntload(&ei[E + e]) : ntload(&ei[2 * (E + (long long)e)]);
            if ((u32)d < (u32)N_NODES) {
                int x = (d >> 12) & 7;
#pragma unroll
                for (int k = 0; k < 8; ++k) c[k] += (x == k);
            }
        }
    }
#pragma unroll
    for (int k = 0; k < 8; ++k) {
#pragma unroll
        for (int m = 1; m <= 32; m <<= 1) c[k] += __shfl_xor(c[k], m, 64);
    }
    if ((tid & 63) == 0) {
#pragma unroll
        for (int k = 0; k < 8; ++k) atomicAdd(&lc[k], c[k]);
    }
    __syncthreads();
    if (tid < 8) blkcnt[blockIdx.x * 8 + tid] = lc[tid];
}

// ---------------- scan per-(block,xcd) counts -> exact queue offsets ----------------
__global__ void qscan_kernel(const int* __restrict__ blkcnt, int* __restrict__ qbase,
                             int* __restrict__ xcdstart, int nblk) {
    __shared__ int lds[256];
    const int t = threadIdx.x;
    const int nseq = nblk * 8;
    const int per = (nseq + 255) / 256;
    const int j0 = t * per;
    const int j1 = min(j0 + per, nseq);
    int sum = 0;
    for (int j = j0; j < j1; ++j) {
        int x = j / nblk, b = j - x * nblk;
        sum += blkcnt[b * 8 + x];
    }
    lds[t] = sum;
    __syncthreads();
    for (int off = 1; off < 256; off <<= 1) {
        int v = (t >= off) ? lds[t - off] : 0;
        __syncthreads();
        lds[t] += v;
        __syncthreads();
    }
    int run = (t > 0) ? lds[t - 1] : 0;
    for (int j = j0; j < j1; ++j) {
        int x = j / nblk, b = j - x * nblk;
        if (b == 0) xcdstart[x] = run;
        qbase[b * 8 + x] = run;
        run += blkcnt[b * 8 + x];
    }
    if (t == 255) xcdstart[8] = lds[255];
}

// ---------------- edge partition: ei -> 8 dense per-XCD queues (SoA src/dst) --------
__global__ __launch_bounds__(256) void ec2_kernel(const int* __restrict__ ei,
                                                  const int* __restrict__ qbase,
                                                  int* __restrict__ qsrc,
                                                  int* __restrict__ qdst,
                                                  const int* __restrict__ flag, int E) {
    __shared__ int cur[8];
    const int tid = threadIdx.x;
    const int lane = tid & 63;
    if (tid < 8) cur[tid] = qbase[blockIdx.x * 8 + tid];
    __syncthreads();
    const int is32 = *flag;
    const int base = blockIdx.x * CHUNK_EC;
    for (int i = tid; i < CHUNK_EC; i += 256) {
        int e = base + i;
        int x = -1, s = 0, d = 0;
        if (e < E) {
            d = is32 ? ntload(&ei[E + e]) : ntload(&ei[2 * (E + (long long)e)]);
            if ((u32)d < (u32)N_NODES) {
                s = is32 ? ntload(&ei[e]) : ntload(&ei[2 * (long long)e]);
                if ((u32)s >= (u32)N_NODES) s = 0;
                x = (d >> 12) & 7;
            }
        }
#pragma unroll
        for (int k = 0; k < 8; ++k) {
            unsigned long long m = __ballot(x == k);
            if (x == k) {
                int rank = __popcll(m & ((1ULL << lane) - 1ULL));
                int bpos = 0;
                if (rank == 0) bpos = atomicAdd(&cur[k], __popcll(m));
                bpos = __shfl(bpos, (int)__ffsll((long long)m) - 1, 64);
                int p = bpos + rank;
                qsrc[p] = s;
                qdst[p] = d;
            }
        }
    }
}

// ---------------- histogram over dense queue (all lanes active, XCD-local atomics) --
__global__ __launch_bounds__(256) void hist2_kernel(const int* __restrict__ qdst,
                                                    const int* __restrict__ xcdstart,
                                                    int* __restrict__ cnt) {
    const int xcd = blockIdx.x & 7;
    const int g = blockIdx.x >> 3;
    const int G = gridDim.x >> 3;
    const int qs = xcdstart[xcd], qe = xcdstart[xcd + 1];
    for (int i = qs + g * 256 + (int)threadIdx.x; i < qe; i += G * 256) {
        int d = ntload(&qdst[i]);
        atomicAdd(&cnt[d], 1);
    }
}

__global__ void scan1_kernel(const int* __restrict__ cnt, int* __restrict__ row,
                             int* __restrict__ fill, int* __restrict__ part, int n) {
    __shared__ int lds[1024];
    int t = threadIdx.x, g = blockIdx.x * 1024 + t;
    int v = (g < n) ? cnt[g] : 0;
    lds[t] = v;
    __syncthreads();
    for (int off = 1; off < 1024; off <<= 1) {
        int x = (t >= off) ? lds[t - off] : 0;
        __syncthreads();
        lds[t] += x;
        __syncthreads();
    }
    if (g < n) { row[g] = lds[t] - v; fill[g] = lds[t]; }  // excl / incl (= row[g+1])
    if (t == 1023) part[blockIdx.x] = lds[t];               // block total
}

__global__ void scan2_kernel(int* __restrict__ part, int nb) {
    __shared__ int lds[1024];
    int t = threadIdx.x;
    int v = (t < nb) ? part[t] : 0;
    lds[t] = v;
    __syncthreads();
    for (int off = 1; off < 1024; off <<= 1) {
        int x = (t >= off) ? lds[t - off] : 0;
        __syncthreads();
        lds[t] += x;
        __syncthreads();
    }
    if (t < nb) part[t] = lds[t] - v;
}

__global__ void scan3_kernel(int* __restrict__ row, int* __restrict__ fill,
                             const int* __restrict__ part,
                             const int* __restrict__ xcdstart, int n) {
    int g = blockIdx.x * 1024 + threadIdx.x;
    if (g < n) { int p = part[blockIdx.x]; row[g] += p; fill[g] += p; }
    if (g == 0) row[n] = xcdstart[8];
}

// ---------------- dense scatter: ONE atomic, no row gather (fill[d] = row[d+1]) -----
__global__ __launch_bounds__(256) void scatter2_kernel(const int* __restrict__ qsrc,
                                                       const int* __restrict__ qdst,
                                                       const int* __restrict__ xcdstart,
                                                       int* __restrict__ fill,
                                                       int* __restrict__ csr) {
    const int xcd = blockIdx.x & 7;
    const int g = blockIdx.x >> 3;
    const int G = gridDim.x >> 3;
    const int qs = xcdstart[xcd], qe = xcdstart[xcd + 1];
    for (int i = qs + g * 256 + (int)threadIdx.x; i < qe; i += G * 256) {
        int d = ntload(&qdst[i]);
        int s = ntload(&qsrc[i]);
        int idx = atomicSub(&fill[d], 1) - 1;
        csr[idx] = s;
    }
}

// ---------------- weight split+permute: W(fp32) -> bf16 hi/lo planes, MFMA-frag ----
// fragment-contiguous layout: frag (ks,ft) for lane l at (ft*4+ks)*512 + l*8.
__global__ void wsplitp_kernel(const float* __restrict__ W, u16* __restrict__ hi,
                               u16* __restrict__ lo) {
    int t = blockIdx.x * 256 + threadIdx.x;  // 2048 threads: f x (ks,quad)
    if (t >= 2048) return;
    const int f = t >> 4, ks = (t >> 2) & 3, quad = t & 3;
    const int dst = ((f >> 4) * 4 + ks) * 512 + (quad * 16 + (f & 15)) * 8;
    const float* src = W + f * 128 + ks * 32 + quad * 8;
    U8 h, l;
#pragma unroll
    for (int j = 0; j < 8; ++j) {
        float v = src[j];
        u16 hh = f2bf(v);
        h.h[j] = hh;
        l.h[j] = f2bf(v - bf2f(hh));
    }
    *(frag8*)(hi + dst) = h.f;
    *(frag8*)(lo + dst) = l.f;
}

// ---------------- x -> bf16 hi plane (gather source; cached store: agg1 re-reads) ----
__global__ void xtobf_kernel(const float* __restrict__ X, u16* __restrict__ out, int n2) {
    int i = blockIdx.x * 256 + threadIdx.x;
    if (i >= n2) return;
    f32x2 v = ntload(&((const f32x2*)X)[i]);
    ((u32*)out)[i] = packbf(v[0], v[1]);
}

// ---------------- mean aggregation over CSR (bf16 rows -> bf16 mean) ----------------
template <int MODE>
__global__ __launch_bounds__(256) void agg_kernel(
    const u16* __restrict__ X, const int* __restrict__ rowstart,
    const int* __restrict__ csr, u16* __restrict__ out,
    const float* __restrict__ bnp) {
    const int wid = (blockIdx.x * 256 + threadIdx.x) >> 6;
    const int lane = threadIdx.x & 63;
    const int g = lane >> 4;
    const int l = lane & 15;
    if (wid >= N_NODES) return;
    const int s = rowstart[wid];
    const int deg = rowstart[wid + 1] - s;
    const u32x4* Xv = (const u32x4*)X;  // row = 16 u32x4
    float av[8] = {0.f, 0.f, 0.f, 0.f, 0.f, 0.f, 0.f, 0.f};
    for (int base = 0; base < deg; base += 64) {
        const int nb = min(deg - base, 64);
        const int myidx = csr[s + base + min(lane, nb - 1)];  // one coalesced load
        int c = 0;
#pragma unroll 4
        for (; c + 4 <= nb; c += 4) {
            const int idx = __shfl(myidx, c + g, 64);
            u32x4 q = Xv[(size_t)idx * 16 + l];
            accum8(av, q);
        }
        if (c < nb) {  // tail: 1..3 neighbors
            const int idx = __shfl(myidx, min(c + g, nb - 1), 64);
            u32x4 q = Xv[(size_t)idx * 16 + l];
            if (c + g < nb) accum8(av, q);
        }
    }
#pragma unroll
    for (int j = 0; j < 8; ++j) {
        av[j] += __shfl_xor(av[j], 16, 64);
        av[j] += __shfl_xor(av[j], 32, 64);
    }
    if (g == 0) {
        const float inv = 1.0f / (float)max(deg, 1);
#pragma unroll
        for (int j = 0; j < 8; ++j) av[j] *= inv;
        if (MODE == 1) {
            if (deg > 0) {
#pragma unroll
                for (int j = 0; j < 8; ++j)
                    av[j] = av[j] * bnp[l * 8 + j] + bnp[128 + l * 8 + j];
            } else {
#pragma unroll
                for (int j = 0; j < 8; ++j) av[j] = 0.f;
            }
        }
        u32x4 o;
        o[0] = packbf(av[0], av[1]); o[1] = packbf(av[2], av[3]);
        o[2] = packbf(av[4], av[5]); o[3] = packbf(av[6], av[7]);
        ((u32x4*)out)[(size_t)wid * 16 + l] = o;  // cached: consumed by gemm
    }
}

// ---------------- fused GEMM v5: register-resident weights + LDS-staged A ----------
// R1-R4 triangulation: ANY per-wave in-k-loop global load (weights OR A) latency-
// serializes the kernel at ~75-85us with all pipes <15%. v5 removes both:
//  - 8 waves (512 thr); wave wv owns output-feature slice [wv*16, wv*16+16):
//    its weight frags (4 planes x 4 ksteps = 16 frag8 = 64 VGPR) loaded ONCE.
//  - grid-stride over 3125 BM=32 row-tiles; A staged into dbuf LDS via
//    global_load_lds (linear dest, source pre-swizzled with c ^= r&15 so LDS
//    fragment reads spread evenly over all bank groups).
//  - one full __syncthreads per tile (stage of t+1 issued right after, lands
//    during compute); LDS-only raw barrier mid-epilogue (no vmcnt drain).
//  - epilogue: shfl row-norm partials + ssrow2[32][8] direct writes (no atomics),
//    shfl-packed direct stores, BN sums in registers -> one atomic set at end.
template <int GM>
__global__ __launch_bounds__(512, 4) void gemm_kernel(
    const u16* __restrict__ A1bf, const float* __restrict__ A2f,
    const u16* __restrict__ A2b, const u16* __restrict__ Wc,
    const float* __restrict__ bias, float* __restrict__ outf,
    u16* __restrict__ outb, float* __restrict__ bnsums) {
    constexpr int TB = (GM == 0) ? 24576 : 16384;  // A1 8K + A2 (x fp32 16K | rhh 8K)
    __shared__ __align__(16) char bufs[2][TB];
    __shared__ float ssrow2[32][8];  // [row][wave] L2-norm partials
    const int tid = threadIdx.x;
    const int lane = tid & 63;
    const int wv = tid >> 6;      // 0..7 = output-feature tile
    const int col = lane & 15;
    const int quad = lane >> 4;

    // ---- weights: this wave's ft slice, all planes/ksteps, register-resident ----
    frag8 wlh[4], wll[4], wrh[4], wrl[4];
#pragma unroll
    for (int ks = 0; ks < 4; ++ks) {
        const int wo = (wv * 4 + ks) * 512 + lane * 8;
        wlh[ks] = *(const frag8*)(Wc + wo);
        wll[ks] = *(const frag8*)(Wc + 16384 + wo);
        wrh[ks] = *(const frag8*)(Wc + 32768 + wo);
        wrl[ks] = *(const frag8*)(Wc + 49152 + wo);
    }
    const float bsv = bias[wv * 16 + col];

    auto stage = [&](char* buf, int trow0) {
        if (GM == 0) {
#pragma unroll
            for (int j = 0; j < 3; ++j) {
                const int m = wv * 3 + j;  // wave-uniform
                if (m < 8) {               // A1: 32 rows x 256B
                    const int s = m * 64 + lane;
                    const int r = s >> 4, c = (s & 15) ^ (r & 15);
                    gload16((const char*)A1bf + (size_t)(trow0 + r) * 256 + (c << 4),
                            buf + m * 1024);
                } else {                   // x fp32: 32 rows x 512B
                    const int s = (m - 8) * 64 + lane;
                    const int r = s >> 5, c = (s & 31) ^ (r & 15);
                    gload16((const char*)A2f + (size_t)(trow0 + r) * 512 + (c << 4),
                            buf + 8192 + (m - 8) * 1024);
                }
            }
        } else {
#pragma unroll
            for (int j = 0; j < 2; ++j) {
                const int m = wv * 2 + j;  // wave-uniform
                const int s = (m & 7) * 64 + lane;
                const int r = s >> 4, c = (s & 15) ^ (r & 15);
                const u16* src = (m < 8) ? A1bf : A2b;
                gload16((const char*)src + (size_t)(trow0 + r) * 256 + (c << 4),
                        buf + (m < 8 ? 0 : 8192) + (m & 7) * 1024);
            }
        }
    };

    float bn1 = 0.f, bn2 = 0.f;
    int cur = 0;
    stage(bufs[0], blockIdx.x * 32);

    for (int t = blockIdx.x; t < NTILES; t += GGRID) {
        __syncthreads();  // buf[cur] staged (vmcnt drained); prev ssrow2 reads done
        const int tn = t + GGRID;
        if (tn < NTILES) stage(bufs[cur ^ 1], tn * 32);

        // ---- k-loop: pure LDS reads + MFMA ----
        f32x4 acc[2];
        acc[0] = (f32x4){0.f, 0.f, 0.f, 0.f};
        acc[1] = (f32x4){0.f, 0.f, 0.f, 0.f};
        char* buf = bufs[cur];
#pragma unroll
        for (int ks = 0; ks < 4; ++ks) {
            frag8 a1[2];
            U8 a2h[2], a2l[2];
#pragma unroll
            for (int mt = 0; mt < 2; ++mt) {
                const int rr = mt * 16 + col;
                const int sw = ((ks * 4 + quad) ^ col) << 4;
                a1[mt] = *(const frag8*)(buf + rr * 256 + sw);
                if (GM == 0) {
                    const int c0 = ks * 8 + quad * 2;
                    f32x4 q0 = *(const f32x4*)(buf + 8192 + rr * 512 + ((c0 ^ col) << 4));
                    f32x4 q1 = *(const f32x4*)(buf + 8192 + rr * 512 + (((c0 + 1) ^ col) << 4));
                    float av[8] = {q0[0], q0[1], q0[2], q0[3], q1[0], q1[1], q1[2], q1[3]};
#pragma unroll
                    for (int j = 0; j < 8; ++j) {
                        u16 hh = f2bf(av[j]);
                        a2h[mt].h[j] = hh;
                        a2l[mt].h[j] = f2bf(av[j] - bf2f(hh));
                    }
                } else {
                    a2h[mt].f = *(const frag8*)(buf + 8192 + rr * 256 + sw);
                }
            }
#pragma unroll
            for (int mt = 0; mt < 2; ++mt) {
                acc[mt] = __builtin_amdgcn_mfma_f32_16x16x32_bf16(a1[mt], wlh[ks], acc[mt], 0, 0, 0);
                acc[mt] = __builtin_amdgcn_mfma_f32_16x16x32_bf16(a1[mt], wll[ks], acc[mt], 0, 0, 0);
                acc[mt] = __builtin_amdgcn_mfma_f32_16x16x32_bf16(a2h[mt].f, wrh[ks], acc[mt], 0, 0, 0);
                if (GM == 0)
                    acc[mt] = __builtin_amdgcn_mfma_f32_16x16x32_bf16(a2l[mt].f, wrh[ks], acc[mt], 0, 0, 0);
                acc[mt] = __builtin_amdgcn_mfma_f32_16x16x32_bf16(a2h[mt].f, wrl[ks], acc[mt], 0, 0, 0);
            }
        }

        // ---- epilogue: bias, cross-feature row-norm, store, BN reg-accum ----
        float tv[2][4], sq[2][4];
#pragma unroll
        for (int mt = 0; mt < 2; ++mt)
#pragma unroll
            for (int r = 0; r < 4; ++r) {
                float v = acc[mt][r] + bsv;
                tv[mt][r] = v;
                sq[mt][r] = v * v;
            }
#pragma unroll
        for (int m = 1; m <= 8; m <<= 1)
#pragma unroll
            for (int mt = 0; mt < 2; ++mt)
#pragma unroll
                for (int r = 0; r < 4; ++r) sq[mt][r] += __shfl_xor(sq[mt][r], m, 64);
        if (col == 0) {
#pragma unroll
            for (int mt = 0; mt < 2; ++mt)
#pragma unroll
                for (int r = 0; r < 4; ++r)
                    ssrow2[mt * 16 + quad * 4 + r][wv] = sq[mt][r];
        }
        ldsbar();  // DS-only barrier: partials visible; staging stays in flight

        const int row0 = t * 32;
#pragma unroll
        for (int mt = 0; mt < 2; ++mt)
#pragma unroll
            for (int r = 0; r < 4; ++r) {
                const int rw = mt * 16 + quad * 4 + r;
                f32x4 p0 = *(const f32x4*)&ssrow2[rw][0];
                f32x4 p4 = *(const f32x4*)&ssrow2[rw][4];
                float ss = ((p0[0] + p0[1]) + (p0[2] + p0[3])) +
                           ((p4[0] + p4[1]) + (p4[2] + p4[3]));
                float inv = 1.0f / fmaxf(sqrtf(ss), 1e-12f);
                float o = tv[mt][r] * inv;
                if (GM == 0) o = fmaxf(o, 0.f);
                float po = __shfl_xor(o, 1, 64);
                if (GM == 0) { bn1 += o; bn2 += o * o; }
                if (!(lane & 1)) {
                    const size_t ridx = (size_t)(row0 + rw) * 64 + wv * 8 + (col >> 1);
                    if (GM == 0) {
                        ((u32*)outb)[ridx] = packbf(o, po);  // cached: rhh reused
                    } else {
                        f32x2 o2; o2[0] = o; o2[1] = po;
                        ntstore(o2, &((f32x2*)outf)[ridx]);  // final output
                    }
                }
            }
        cur ^= 1;
    }

    if (GM == 0) {
        bn1 += __shfl_xor(bn1, 16, 64); bn1 += __shfl_xor(bn1, 32, 64);
        bn2 += __shfl_xor(bn2, 16, 64); bn2 += __shfl_xor(bn2, 32, 64);
        if (lane < 16) {  // quad==0 lanes hold per-feature totals
            const int slot = (blockIdx.x & 7) * 256;
            atomicAdd(&bnsums[slot + wv * 16 + lane], bn1);
            atomicAdd(&bnsums[slot + 128 + wv * 16 + lane], bn2);
        }
    }
}

// ---------------- BN finalize: scale/shift from 8-slot sums ----------------
__global__ void bnfin_kernel(const float* __restrict__ sums, const float* __restrict__ gamma,
                             const float* __restrict__ beta, float* __restrict__ bnp) {
    int f = threadIdx.x;
    if (f >= 128) return;
    float s1 = 0.f, s2 = 0.f;
#pragma unroll
    for (int k = 0; k < 8; ++k) {
        s1 += sums[k * 256 + f];
        s2 += sums[k * 256 + 128 + f];
    }
    const float invN = 1.0f / (float)N_NODES;
    float mu = s1 * invN;
    float var = s2 * invN - mu * mu;
    float sc = gamma[f] * rsqrtf(fmaxf(var, 0.f) + 1e-5f);
    bnp[f] = sc;
    bnp[128 + f] = beta[f] - mu * sc;
}

// ---------------- layer-2 weight prep: Wr2' = s .* Wr2 (split+permute), bias2' ----
__global__ void wprep_kernel(const float* __restrict__ Wr2, const float* __restrict__ bl2,
                             const float* __restrict__ bnp, u16* __restrict__ wh,
                             u16* __restrict__ wl, float* __restrict__ bias2p) {
    __shared__ float p[2];
    const int f = blockIdx.x;
    const int k = threadIdx.x;  // 128 threads
    float w = Wr2[f * 128 + k];
    float contrib = w * bnp[128 + k];
    float v = w * bnp[k];
    u16 h = f2bf(v);
    const int ks = k >> 5, quad = (k >> 3) & 3, j = k & 7;
    const int dst = ((f >> 4) * 4 + ks) * 512 + (quad * 16 + (f & 15)) * 8 + j;
    wh[dst] = h;
    wl[dst] = f2bf(v - bf2f(h));
#pragma unroll
    for (int m = 1; m <= 32; m <<= 1) contrib += __shfl_xor(contrib, m, 64);
    if ((k & 63) == 0) p[k >> 6] = contrib;
    __syncthreads();
    if (k == 0) bias2p[f] = bl2[f] + p[0] + p[1];
}

extern "C" void kernel_launch(void* const* d_in, const int* in_sizes, int n_in,
                              void* d_out, int out_size, void* d_ws, size_t ws_size,
                              hipStream_t stream) {
    const int N = N_NODES;
    const int E = in_sizes[1] / 2;
    const int nblk2 = (E + CHUNK_EC - 1) / CHUNK_EC;

    const float* x     = (const float*)d_in[0];
    const int*   ei    = (const int*)d_in[1];
    const float* Wl1   = (const float*)d_in[2];
    const float* bl1   = (const float*)d_in[3];
    const float* Wr1   = (const float*)d_in[4];
    const float* gamma = (const float*)d_in[5];
    const float* beta  = (const float*)d_in[6];
    const float* Wl2   = (const float*)d_in[7];
    const float* bl2   = (const float*)d_in[8];
    const float* Wr2   = (const float*)d_in[9];
    float* outp = (float*)d_out;

    char* ws = (char*)d_ws;
    size_t off = 0;
    auto alloc = [&](size_t b) { size_t r = off; off += (b + 255) & ~(size_t)255; return r; };
    int*   flag     = (int*)  (ws + alloc(4));
    int*   cnt      = (int*)  (ws + alloc((size_t)N * 4));
    int*   rowstart = (int*)  (ws + alloc((size_t)(N + 1) * 4));
    int*   fill     = (int*)  (ws + alloc((size_t)N * 4));
    int*   partials = (int*)  (ws + alloc(4096));
    int*   xcdstart = (int*)  (ws + alloc(64));
    int*   blkcnt   = (int*)  (ws + alloc((size_t)nblk2 * 8 * 4));
    int*   qbase    = (int*)  (ws + alloc((size_t)nblk2 * 8 * 4));
    int*   csr      = (int*)  (ws + alloc((size_t)E * 4));
    int*   qsrc     = (int*)  (ws + alloc((size_t)E * 4));
    int*   qdst     = (int*)  (ws + alloc((size_t)E * 4));
    float* bnsums   = (float*)(ws + alloc(2048 * 4));   // 8 slots x 256
    float* bnp      = (float*)(ws + alloc(256 * 4));
    float* bias2p   = (float*)(ws + alloc(128 * 4));
    u16*   w1c      = (u16*)  (ws + alloc(65536 * 2));  // 4 planes: lh,ll,rh,rl
    u16*   w2c      = (u16*)  (ws + alloc(65536 * 2));  // 4 planes: lh,ll,rsh,rsl
    u16*   xh       = (u16*)  (ws + alloc((size_t)N * 128 * 2));
    u16*   meanbf   = (u16*)  (ws + alloc((size_t)N * 128 * 2));
    u16*   rhh      = (u16*)  (ws + alloc((size_t)N * 128 * 2));  // ~98 MB total

    hipMemsetAsync(cnt, 0, (size_t)N * 4, stream);
    hipMemsetAsync(bnsums, 0, 2048 * 4, stream);

    // ---- CSR build: partition edges into dense per-XCD queues, then dense passes ----
    detect_kernel<<<1, 64, 0, stream>>>(ei, flag, E);
    eccnt_kernel<<<nblk2, 256, 0, stream>>>(ei, blkcnt, flag, E);
    qscan_kernel<<<1, 256, 0, stream>>>(blkcnt, qbase, xcdstart, nblk2);
    ec2_kernel<<<nblk2, 256, 0, stream>>>(ei, qbase, qsrc, qdst, flag, E);
    hist2_kernel<<<2048, 256, 0, stream>>>(qdst, xcdstart, cnt);
    const int nb = (N + 1023) / 1024;
    scan1_kernel<<<nb, 1024, 0, stream>>>(cnt, rowstart, fill, partials, N);
    scan2_kernel<<<1, 1024, 0, stream>>>(partials, nb);
    scan3_kernel<<<nb, 1024, 0, stream>>>(rowstart, fill, partials, xcdstart, N);
    scatter2_kernel<<<2048, 256, 0, stream>>>(qsrc, qdst, xcdstart, fill, csr);

    wsplitp_kernel<<<8, 256, 0, stream>>>(Wl1, w1c, w1c + 16384);
    wsplitp_kernel<<<8, 256, 0, stream>>>(Wr1, w1c + 32768, w1c + 49152);
    wsplitp_kernel<<<8, 256, 0, stream>>>(Wl2, w2c, w2c + 16384);
    xtobf_kernel<<<(N * 64 + 255) / 256, 256, 0, stream>>>(x, xh, N * 64);

    // conv1
    agg_kernel<0><<<(N + 3) / 4, 256, 0, stream>>>(xh, rowstart, csr, meanbf, nullptr);
    gemm_kernel<0><<<GGRID, 512, 0, stream>>>(meanbf, x, nullptr, w1c,
                                              bl1, nullptr, rhh, bnsums);
    bnfin_kernel<<<1, 128, 0, stream>>>(bnsums, gamma, beta, bnp);
    wprep_kernel<<<128, 128, 0, stream>>>(Wr2, bl2, bnp, w2c + 32768, w2c + 49152, bias2p);
    // conv2
    agg_kernel<1><<<(N + 3) / 4, 256, 0, stream>>>(rhh, rowstart, csr, meanbf, bnp);
    gemm_kernel<1><<<GGRID, 512, 0, stream>>>(meanbf, nullptr, rhh, w2c,
                                              bias2p, outp, nullptr, nullptr);
}

// Round 6
// 543.559 us; speedup vs baseline: 1.0465x; 1.0465x over previous
//
#include <hip/hip_runtime.h>

typedef unsigned short u16;
typedef unsigned int   u32;

#define N_NODES 100000
#define CHUNK_EC 2048
#define NTILES 3125   // N_NODES / 32, exact
#define GGRID  512

typedef short frag8 __attribute__((ext_vector_type(8)));
typedef float f32x4 __attribute__((ext_vector_type(4)));
typedef float f32x2 __attribute__((ext_vector_type(2)));
typedef u32   u32x4 __attribute__((ext_vector_type(4)));

template <typename T>
__device__ __forceinline__ T ntload(const T* p) { return __builtin_nontemporal_load(p); }
template <typename T>
__device__ __forceinline__ void ntstore(T v, T* p) { __builtin_nontemporal_store(v, p); }

__device__ __forceinline__ float bf2f(u16 h) {
    union { u32 u; float f; } c; c.u = ((u32)h) << 16; return c.f;
}
__device__ __forceinline__ u16 f2bf(float f) {
    union { float f; u32 u; } c; c.f = f;
    u32 u = c.u;
    return (u16)((u + 0x7FFFu + ((u >> 16) & 1u)) >> 16);
}
__device__ __forceinline__ float2 bfx2(u32 u) {
    union { u32 u; float f; } lo, hi;
    lo.u = u << 16; hi.u = u & 0xFFFF0000u;
    return make_float2(lo.f, hi.f);
}
__device__ __forceinline__ u32 packbf(float a, float b) {
    return (u32)f2bf(a) | ((u32)f2bf(b) << 16);
}
__device__ __forceinline__ void accum8(float* av, u32x4 q) {
    float2 p0 = bfx2(q[0]), p1 = bfx2(q[1]), p2 = bfx2(q[2]), p3 = bfx2(q[3]);
    av[0] += p0.x; av[1] += p0.y; av[2] += p1.x; av[3] += p1.y;
    av[4] += p2.x; av[5] += p2.y; av[6] += p3.x; av[7] += p3.y;
}

// global -> LDS direct DMA, 16B/lane, linear LDS dest (wave-uniform base + lane*16);
// global source address is PER-LANE (m104) -> fragment-ordered staging.
__device__ __forceinline__ void gload16(const void* g, void* lds) {
    __builtin_amdgcn_global_load_lds(
        (const __attribute__((address_space(1))) unsigned int*)g,
        (__attribute__((address_space(3))) unsigned int*)lds, 16, 0, 0);
}

// LDS-only barrier: orders DS ops without draining vmcnt (keeps staging in flight)
__device__ __forceinline__ void ldsbar() {
    asm volatile("s_waitcnt lgkmcnt(0)" ::: "memory");
    __builtin_amdgcn_s_barrier();
}

union U8 { frag8 f; u16 h[8]; };

// ---------------- edge-index layout detect (int32 vs int64) ----------------
__global__ void detect_kernel(const int* __restrict__ ei, int* __restrict__ flag, int E) {
    int any = 0;
    int lim = min(2048, 2 * E);
    for (int i = 1 + 2 * (int)threadIdx.x; i < lim; i += 128) any |= ei[i];
    unsigned long long b = __ballot(any != 0);
    if (threadIdx.x == 0) *flag = (b != 0ULL) ? 1 : 0;  // 1 => int32 layout
}

// ---------------- per-(block,xcd) edge counts (register counters, no atomics) ------
__global__ __launch_bounds__(256) void eccnt_kernel(const int* __restrict__ ei,
                                                    int* __restrict__ blkcnt,
                                                    const int* __restrict__ flag, int E) {
    __shared__ int lc[8];
    const int tid = threadIdx.x;
    if (tid < 8) lc[tid] = 0;
    __syncthreads();
    const int is32 = *flag;
    const int base = blockIdx.x * CHUNK_EC;
    int c[8] = {0, 0, 0, 0, 0, 0, 0, 0};
    for (int i = tid; i < CHUNK_EC; i += 256) {
        int e = base + i;
        if (e < E) {
            int d = is32 ? ntload(&ei[E + e]) : ntload(&ei[2 * (E + (long long)e)]);
            if ((u32)d < (u32)N_NODES) {
                int x = (d >> 12) & 7;
#pragma unroll
                for (int k = 0; k < 8; ++k) c[k] += (x == k);
            }
        }
    }
#pragma unroll
    for (int k = 0; k < 8; ++k) {
#pragma unroll
        for (int m = 1; m <= 32; m <<= 1) c[k] += __shfl_xor(c[k], m, 64);
    }
    if ((tid & 63) == 0) {
#pragma unroll
        for (int k = 0; k < 8; ++k) atomicAdd(&lc[k], c[k]);
    }
    __syncthreads();
    if (tid < 8) blkcnt[blockIdx.x * 8 + tid] = lc[tid];
}

// ---------------- scan per-(block,xcd) counts -> exact queue offsets ----------------
__global__ void qscan_kernel(const int* __restrict__ blkcnt, int* __restrict__ qbase,
                             int* __restrict__ xcdstart, int nblk) {
    __shared__ int lds[256];
    const int t = threadIdx.x;
    const int nseq = nblk * 8;
    const int per = (nseq + 255) / 256;
    const int j0 = t * per;
    const int j1 = min(j0 + per, nseq);
    int sum = 0;
    for (int j = j0; j < j1; ++j) {
        int x = j / nblk, b = j - x * nblk;
        sum += blkcnt[b * 8 + x];
    }
    lds[t] = sum;
    __syncthreads();
    for (int off = 1; off < 256; off <<= 1) {
        int v = (t >= off) ? lds[t - off] : 0;
        __syncthreads();
        lds[t] += v;
        __syncthreads();
    }
    int run = (t > 0) ? lds[t - 1] : 0;
    for (int j = j0; j < j1; ++j) {
        int x = j / nblk, b = j - x * nblk;
        if (b == 0) xcdstart[x] = run;
        qbase[b * 8 + x] = run;
        run += blkcnt[b * 8 + x];
    }
    if (t == 255) xcdstart[8] = lds[255];
}

// ---------------- edge partition: ei -> 8 dense per-XCD queues (SoA src/dst) --------
__global__ __launch_bounds__(256) void ec2_kernel(const int* __restrict__ ei,
                                                  const int* __restrict__ qbase,
                                                  int* __restrict__ qsrc,
                                                  int* __restrict__ qdst,
                                                  const int* __restrict__ flag, int E) {
    __shared__ int cur[8];
    const int tid = threadIdx.x;
    const int lane = tid & 63;
    if (tid < 8) cur[tid] = qbase[blockIdx.x * 8 + tid];
    __syncthreads();
    const int is32 = *flag;
    const int base = blockIdx.x * CHUNK_EC;
    for (int i = tid; i < CHUNK_EC; i += 256) {
        int e = base + i;
        int x = -1, s = 0, d = 0;
        if (e < E) {
            d = is32 ? ntload(&ei[E + e]) : ntload(&ei[2 * (E + (long long)e)]);
            if ((u32)d < (u32)N_NODES) {
                s = is32 ? ntload(&ei[e]) : ntload(&ei[2 * (long long)e]);
                if ((u32)s >= (u32)N_NODES) s = 0;
                x = (d >> 12) & 7;
            }
        }
#pragma unroll
        for (int k = 0; k < 8; ++k) {
            unsigned long long m = __ballot(x == k);
            if (x == k) {
                int rank = __popcll(m & ((1ULL << lane) - 1ULL));
                int bpos = 0;
                if (rank == 0) bpos = atomicAdd(&cur[k], __popcll(m));
                bpos = __shfl(bpos, (int)__ffsll((long long)m) - 1, 64);
                int p = bpos + rank;
                qsrc[p] = s;
                qdst[p] = d;
            }
        }
    }
}

// ---------------- histogram over dense queue (all lanes active, XCD-local atomics) --
__global__ __launch_bounds__(256) void hist2_kernel(const int* __restrict__ qdst,
                                                    const int* __restrict__ xcdstart,
                                                    int* __restrict__ cnt) {
    const int xcd = blockIdx.x & 7;
    const int g = blockIdx.x >> 3;
    const int G = gridDim.x >> 3;
    const int qs = xcdstart[xcd], qe = xcdstart[xcd + 1];
    for (int i = qs + g * 256 + (int)threadIdx.x; i < qe; i += G * 256) {
        int d = ntload(&qdst[i]);
        atomicAdd(&cnt[d], 1);
    }
}

__global__ void scan1_kernel(const int* __restrict__ cnt, int* __restrict__ row,
                             int* __restrict__ fill, int* __restrict__ part, int n) {
    __shared__ int lds[1024];
    int t = threadIdx.x, g = blockIdx.x * 1024 + t;
    int v = (g < n) ? cnt[g] : 0;
    lds[t] = v;
    __syncthreads();
    for (int off = 1; off < 1024; off <<= 1) {
        int x = (t >= off) ? lds[t - off] : 0;
        __syncthreads();
        lds[t] += x;
        __syncthreads();
    }
    if (g < n) { row[g] = lds[t] - v; fill[g] = lds[t]; }  // excl / incl (= row[g+1])
    if (t == 1023) part[blockIdx.x] = lds[t];               // block total
}

__global__ void scan2_kernel(int* __restrict__ part, int nb) {
    __shared__ int lds[1024];
    int t = threadIdx.x;
    int v = (t < nb) ? part[t] : 0;
    lds[t] = v;
    __syncthreads();
    for (int off = 1; off < 1024; off <<= 1) {
        int x = (t >= off) ? lds[t - off] : 0;
        __syncthreads();
        lds[t] += x;
        __syncthreads();
    }
    if (t < nb) part[t] = lds[t] - v;
}

__global__ void scan3_kernel(int* __restrict__ row, int* __restrict__ fill,
                             const int* __restrict__ part,
                             const int* __restrict__ xcdstart, int n) {
    int g = blockIdx.x * 1024 + threadIdx.x;
    if (g < n) { int p = part[blockIdx.x]; row[g] += p; fill[g] += p; }
    if (g == 0) row[n] = xcdstart[8];
}

// ---------------- dense scatter: ONE atomic, no row gather (fill[d] = row[d+1]) -----
__global__ __launch_bounds__(256) void scatter2_kernel(const int* __restrict__ qsrc,
                                                       const int* __restrict__ qdst,
                                                       const int* __restrict__ xcdstart,
                                                       int* __restrict__ fill,
                                                       int* __restrict__ csr) {
    const int xcd = blockIdx.x & 7;
    const int g = blockIdx.x >> 3;
    const int G = gridDim.x >> 3;
    const int qs = xcdstart[xcd], qe = xcdstart[xcd + 1];
    for (int i = qs + g * 256 + (int)threadIdx.x; i < qe; i += G * 256) {
        int d = ntload(&qdst[i]);
        int s = ntload(&qsrc[i]);
        int idx = atomicSub(&fill[d], 1) - 1;
        csr[idx] = s;
    }
}

// ---------------- weight split+permute: W(fp32) -> bf16 hi/lo planes, MFMA-frag ----
// fragment-contiguous layout: frag (ks,ft) for lane l at (ft*4+ks)*512 + l*8.
__global__ void wsplitp_kernel(const float* __restrict__ W, u16* __restrict__ hi,
                               u16* __restrict__ lo) {
    int t = blockIdx.x * 256 + threadIdx.x;  // 2048 threads: f x (ks,quad)
    if (t >= 2048) return;
    const int f = t >> 4, ks = (t >> 2) & 3, quad = t & 3;
    const int dst = ((f >> 4) * 4 + ks) * 512 + (quad * 16 + (f & 15)) * 8;
    const float* src = W + f * 128 + ks * 32 + quad * 8;
    U8 h, l;
#pragma unroll
    for (int j = 0; j < 8; ++j) {
        float v = src[j];
        u16 hh = f2bf(v);
        h.h[j] = hh;
        l.h[j] = f2bf(v - bf2f(hh));
    }
    *(frag8*)(hi + dst) = h.f;
    *(frag8*)(lo + dst) = l.f;
}

// ---------------- x -> bf16 hi + lo planes (hi: agg gather + gemm; lo: gemm) -------
__global__ void xtobf_kernel(const float* __restrict__ X, u16* __restrict__ outh,
                             u16* __restrict__ outl, int n2) {
    int i = blockIdx.x * 256 + threadIdx.x;
    if (i >= n2) return;
    f32x2 v = ntload(&((const f32x2*)X)[i]);
    u16 h0 = f2bf(v[0]), h1 = f2bf(v[1]);
    ((u32*)outh)[i] = (u32)h0 | ((u32)h1 << 16);
    ((u32*)outl)[i] = (u32)f2bf(v[0] - bf2f(h0)) | ((u32)f2bf(v[1] - bf2f(h1)) << 16);
}

// ---------------- mean aggregation over CSR (bf16 rows -> bf16 mean) ----------------
template <int MODE>
__global__ __launch_bounds__(256) void agg_kernel(
    const u16* __restrict__ X, const int* __restrict__ rowstart,
    const int* __restrict__ csr, u16* __restrict__ out,
    const float* __restrict__ bnp) {
    const int wid = (blockIdx.x * 256 + threadIdx.x) >> 6;
    const int lane = threadIdx.x & 63;
    const int g = lane >> 4;
    const int l = lane & 15;
    if (wid >= N_NODES) return;
    const int s = rowstart[wid];
    const int deg = rowstart[wid + 1] - s;
    const u32x4* Xv = (const u32x4*)X;  // row = 16 u32x4
    float av[8] = {0.f, 0.f, 0.f, 0.f, 0.f, 0.f, 0.f, 0.f};
    for (int base = 0; base < deg; base += 64) {
        const int nb = min(deg - base, 64);
        const int myidx = csr[s + base + min(lane, nb - 1)];  // one coalesced load
        int c = 0;
#pragma unroll 4
        for (; c + 4 <= nb; c += 4) {
            const int idx = __shfl(myidx, c + g, 64);
            u32x4 q = Xv[(size_t)idx * 16 + l];
            accum8(av, q);
        }
        if (c < nb) {  // tail: 1..3 neighbors
            const int idx = __shfl(myidx, min(c + g, nb - 1), 64);
            u32x4 q = Xv[(size_t)idx * 16 + l];
            if (c + g < nb) accum8(av, q);
        }
    }
#pragma unroll
    for (int j = 0; j < 8; ++j) {
        av[j] += __shfl_xor(av[j], 16, 64);
        av[j] += __shfl_xor(av[j], 32, 64);
    }
    if (g == 0) {
        const float inv = 1.0f / (float)max(deg, 1);
#pragma unroll
        for (int j = 0; j < 8; ++j) av[j] *= inv;
        if (MODE == 1) {
            if (deg > 0) {
#pragma unroll
                for (int j = 0; j < 8; ++j)
                    av[j] = av[j] * bnp[l * 8 + j] + bnp[128 + l * 8 + j];
            } else {
#pragma unroll
                for (int j = 0; j < 8; ++j) av[j] = 0.f;
            }
        }
        u32x4 o;
        o[0] = packbf(av[0], av[1]); o[1] = packbf(av[2], av[3]);
        o[2] = packbf(av[4], av[5]); o[3] = packbf(av[6], av[7]);
        ((u32x4*)out)[(size_t)wid * 16 + l] = o;  // cached: consumed by gemm
    }
}

// ---------------- fused GEMM v6: reg weights (no spill) + frag-ordered LDS A -------
// R5 post-mortem: launch_bounds(512,4) budget 128 < ~130 live regs -> weight frags
// SPILLED to scratch (VGPR_Count=64, scratch traffic = +60MB FETCH/WRITE, 40% VALU).
// v6: (512,2) -> 256-reg budget, weights provably resident. All bf16 A operands
// (x pre-split into xh/xl planes by xtobf) -> zero in-loop VALU split. Staging is
// FRAGMENT-ORDERED: global source per-lane addressed so LDS = frag m at m*1KB,
// lane at lane*16 -> ds_read_b128 lane-contiguous, ZERO bank conflicts; each
// staging instr reads 16 rows x 64B full lines. Output via LDS bounce -> full-line
// linear stores. BN sums in registers -> one 8-slot atomic set at end.
template <int GM>
__global__ __launch_bounds__(512, 2) void gemm_kernel(
    const u16* __restrict__ A1bf, const u16* __restrict__ A2h_,
    const u16* __restrict__ A2l_, const u16* __restrict__ Wc,
    const float* __restrict__ bias, float* __restrict__ outf,
    u16* __restrict__ outb, float* __restrict__ bnsums) {
    constexpr int NREG = (GM == 0) ? 3 : 2;       // staging regions (A1,A2h[,A2l])
    constexpr int TB = NREG * 8192;               // bytes per buffer
    constexpr int OB = (GM == 0) ? 8192 : 16384;  // out-bounce bytes
    __shared__ __align__(16) char bufs[2][TB];
    __shared__ __align__(16) char outbuf[OB];
    __shared__ float ssrow2[32][8];  // [row][wave] L2-norm partials
    const int tid = threadIdx.x;
    const int lane = tid & 63;
    const int wv = tid >> 6;      // 0..7 = output-feature slice
    const int col = lane & 15;
    const int quad = lane >> 4;

    auto stage = [&](char* buf, int trow0) {
        // chunk m = rgn*8 + c; c=(mt<<2)|ks; frag-ordered: LDS m*1KB + lane*16
        // global: row (trow0 + mt*16 + col)*256B + ks*64 + quad*16 (full 64B lines)
#pragma unroll
        for (int j = 0; j < NREG; ++j) {
            const int m = j * 8 + wv;  // wave-uniform; wv>=... each wave does chunk wv of each region
            const int c = m & 7;
            const int rgn = m >> 3;
            const u16* srcp = (rgn == 0) ? A1bf : (rgn == 1) ? A2h_ : A2l_;
            gload16((const char*)srcp +
                        (size_t)(trow0 + ((c >> 2) << 4) + (lane & 15)) * 256 +
                        ((c & 3) << 6) + ((lane >> 4) << 4),
                    buf + m * 1024);
        }
    };

    // ---- weights: this wave's ft slice, all planes/ksteps, register-resident ----
    int cur = 0;
    stage(bufs[0], blockIdx.x * 32);
    frag8 wlh[4], wll[4], wrh[4], wrl[4];
#pragma unroll
    for (int ks = 0; ks < 4; ++ks) {
        const int wo = (wv * 4 + ks) * 512 + lane * 8;
        wlh[ks] = *(const frag8*)(Wc + wo);
        wll[ks] = *(const frag8*)(Wc + 16384 + wo);
        wrh[ks] = *(const frag8*)(Wc + 32768 + wo);
        wrl[ks] = *(const frag8*)(Wc + 49152 + wo);
    }
    const float bsv = bias[wv * 16 + col];
    float bn1 = 0.f, bn2 = 0.f;

    for (int t = blockIdx.x; t < NTILES; t += GGRID) {
        __syncthreads();  // drains vmcnt: buf[cur] fully staged; prev-tile LDS done
        const int tn = t + GGRID;
        if (tn < NTILES) stage(bufs[cur ^ 1], tn * 32);

        // ---- k-loop: lane-contiguous LDS fragment reads + MFMA, zero VALU ----
        f32x4 acc[2];
        acc[0] = (f32x4){0.f, 0.f, 0.f, 0.f};
        acc[1] = (f32x4){0.f, 0.f, 0.f, 0.f};
        char* buf = bufs[cur];
#pragma unroll
        for (int ks = 0; ks < 4; ++ks) {
            frag8 a1[2], a2h[2], a2l[2];
#pragma unroll
            for (int mt = 0; mt < 2; ++mt) {
                const int fo = ((mt << 2) + ks) * 1024 + lane * 16;
                a1[mt] = *(const frag8*)(buf + fo);
                a2h[mt] = *(const frag8*)(buf + 8192 + fo);
                if (GM == 0) a2l[mt] = *(const frag8*)(buf + 16384 + fo);
            }
#pragma unroll
            for (int mt = 0; mt < 2; ++mt) {
                acc[mt] = __builtin_amdgcn_mfma_f32_16x16x32_bf16(a1[mt], wlh[ks], acc[mt], 0, 0, 0);
                acc[mt] = __builtin_amdgcn_mfma_f32_16x16x32_bf16(a1[mt], wll[ks], acc[mt], 0, 0, 0);
                acc[mt] = __builtin_amdgcn_mfma_f32_16x16x32_bf16(a2h[mt], wrh[ks], acc[mt], 0, 0, 0);
                if (GM == 0)
                    acc[mt] = __builtin_amdgcn_mfma_f32_16x16x32_bf16(a2l[mt], wrh[ks], acc[mt], 0, 0, 0);
                acc[mt] = __builtin_amdgcn_mfma_f32_16x16x32_bf16(a2h[mt], wrl[ks], acc[mt], 0, 0, 0);
            }
        }

        // ---- epilogue: bias, cross-wave row-norm, LDS-bounce store, BN accum ----
        float tv[2][4], sq[2][4];
#pragma unroll
        for (int mt = 0; mt < 2; ++mt)
#pragma unroll
            for (int r = 0; r < 4; ++r) {
                float v = acc[mt][r] + bsv;
                tv[mt][r] = v;
                sq[mt][r] = v * v;
            }
#pragma unroll
        for (int m = 1; m <= 8; m <<= 1)
#pragma unroll
            for (int mt = 0; mt < 2; ++mt)
#pragma unroll
                for (int r = 0; r < 4; ++r) sq[mt][r] += __shfl_xor(sq[mt][r], m, 64);
        if (col == 0) {
#pragma unroll
            for (int mt = 0; mt < 2; ++mt)
#pragma unroll
                for (int r = 0; r < 4; ++r)
                    ssrow2[mt * 16 + quad * 4 + r][wv] = sq[mt][r];
        }
        ldsbar();  // partials visible; staging stays in flight

#pragma unroll
        for (int mt = 0; mt < 2; ++mt)
#pragma unroll
            for (int r = 0; r < 4; ++r) {
                const int rw = mt * 16 + quad * 4 + r;
                f32x4 p0 = *(const f32x4*)&ssrow2[rw][0];
                f32x4 p4 = *(const f32x4*)&ssrow2[rw][4];
                float ss = ((p0[0] + p0[1]) + (p0[2] + p0[3])) +
                           ((p4[0] + p4[1]) + (p4[2] + p4[3]));
                float inv = 1.0f / fmaxf(sqrtf(ss), 1e-12f);
                float o = tv[mt][r] * inv;
                if (GM == 0) {
                    o = fmaxf(o, 0.f);
                    bn1 += o; bn2 += o * o;
                    float po = __shfl_xor(o, 1, 64);
                    if (!(lane & 1))
                        ((u32*)outbuf)[rw * 64 + wv * 8 + (col >> 1)] = packbf(o, po);
                } else {
                    ((float*)outbuf)[rw * 128 + wv * 16 + col] = o;
                }
            }
        ldsbar();  // out-bounce complete

        // ---- linear full-line global write ----
        const size_t rowbase = (size_t)t * 32;
        if (GM == 0) {
            u32x4 v = *(const u32x4*)(outbuf + tid * 16);
            *(u32x4*)((char*)outb + rowbase * 256 + tid * 16) = v;  // cached: rhh reused
        } else {
            f32x4 v0 = *(const f32x4*)(outbuf + tid * 32);
            f32x4 v1 = *(const f32x4*)(outbuf + tid * 32 + 16);
            ntstore(v0, (f32x4*)((char*)outf + rowbase * 512 + tid * 32));
            ntstore(v1, (f32x4*)((char*)outf + rowbase * 512 + tid * 32 + 16));
        }
        cur ^= 1;
    }

    if (GM == 0) {
        bn1 += __shfl_xor(bn1, 16, 64); bn1 += __shfl_xor(bn1, 32, 64);
        bn2 += __shfl_xor(bn2, 16, 64); bn2 += __shfl_xor(bn2, 32, 64);
        if (lane < 16) {  // quad==0 lanes hold per-feature totals
            const int slot = (blockIdx.x & 7) * 256;
            atomicAdd(&bnsums[slot + wv * 16 + lane], bn1);
            atomicAdd(&bnsums[slot + 128 + wv * 16 + lane], bn2);
        }
    }
}

// ---------------- BN finalize: scale/shift from 8-slot sums ----------------
__global__ void bnfin_kernel(const float* __restrict__ sums, const float* __restrict__ gamma,
                             const float* __restrict__ beta, float* __restrict__ bnp) {
    int f = threadIdx.x;
    if (f >= 128) return;
    float s1 = 0.f, s2 = 0.f;
#pragma unroll
    for (int k = 0; k < 8; ++k) {
        s1 += sums[k * 256 + f];
        s2 += sums[k * 256 + 128 + f];
    }
    const float invN = 1.0f / (float)N_NODES;
    float mu = s1 * invN;
    float var = s2 * invN - mu * mu;
    float sc = gamma[f] * rsqrtf(fmaxf(var, 0.f) + 1e-5f);
    bnp[f] = sc;
    bnp[128 + f] = beta[f] - mu * sc;
}

// ---------------- layer-2 weight prep: Wr2' = s .* Wr2 (split+permute), bias2' ----
__global__ void wprep_kernel(const float* __restrict__ Wr2, const float* __restrict__ bl2,
                             const float* __restrict__ bnp, u16* __restrict__ wh,
                             u16* __restrict__ wl, float* __restrict__ bias2p) {
    __shared__ float p[2];
    const int f = blockIdx.x;
    const int k = threadIdx.x;  // 128 threads
    float w = Wr2[f * 128 + k];
    float contrib = w * bnp[128 + k];
    float v = w * bnp[k];
    u16 h = f2bf(v);
    const int ks = k >> 5, quad = (k >> 3) & 3, j = k & 7;
    const int dst = ((f >> 4) * 4 + ks) * 512 + (quad * 16 + (f & 15)) * 8 + j;
    wh[dst] = h;
    wl[dst] = f2bf(v - bf2f(h));
#pragma unroll
    for (int m = 1; m <= 32; m <<= 1) contrib += __shfl_xor(contrib, m, 64);
    if ((k & 63) == 0) p[k >> 6] = contrib;
    __syncthreads();
    if (k == 0) bias2p[f] = bl2[f] + p[0] + p[1];
}

extern "C" void kernel_launch(void* const* d_in, const int* in_sizes, int n_in,
                              void* d_out, int out_size, void* d_ws, size_t ws_size,
                              hipStream_t stream) {
    const int N = N_NODES;
    const int E = in_sizes[1] / 2;
    const int nblk2 = (E + CHUNK_EC - 1) / CHUNK_EC;

    const float* x     = (const float*)d_in[0];
    const int*   ei    = (const int*)d_in[1];
    const float* Wl1   = (const float*)d_in[2];
    const float* bl1   = (const float*)d_in[3];
    const float* Wr1   = (const float*)d_in[4];
    const float* gamma = (const float*)d_in[5];
    const float* beta  = (const float*)d_in[6];
    const float* Wl2   = (const float*)d_in[7];
    const float* bl2   = (const float*)d_in[8];
    const float* Wr2   = (const float*)d_in[9];
    float* outp = (float*)d_out;

    char* ws = (char*)d_ws;
    size_t off = 0;
    auto alloc = [&](size_t b) { size_t r = off; off += (b + 255) & ~(size_t)255; return r; };
    int*   flag     = (int*)  (ws + alloc(4));
    int*   cnt      = (int*)  (ws + alloc((size_t)N * 4));
    int*   rowstart = (int*)  (ws + alloc((size_t)(N + 1) * 4));
    int*   fill     = (int*)  (ws + alloc((size_t)N * 4));
    int*   partials = (int*)  (ws + alloc(4096));
    int*   xcdstart = (int*)  (ws + alloc(64));
    int*   blkcnt   = (int*)  (ws + alloc((size_t)nblk2 * 8 * 4));
    int*   qbase    = (int*)  (ws + alloc((size_t)nblk2 * 8 * 4));
    int*   csr      = (int*)  (ws + alloc((size_t)E * 4));
    int*   qsrc     = (int*)  (ws + alloc((size_t)E * 4));
    int*   qdst     = (int*)  (ws + alloc((size_t)E * 4));
    float* bnsums   = (float*)(ws + alloc(2048 * 4));   // 8 slots x 256
    float* bnp      = (float*)(ws + alloc(256 * 4));
    float* bias2p   = (float*)(ws + alloc(128 * 4));
    u16*   w1c      = (u16*)  (ws + alloc(65536 * 2));  // 4 planes: lh,ll,rh,rl
    u16*   w2c      = (u16*)  (ws + alloc(65536 * 2));  // 4 planes: lh,ll,rsh,rsl
    u16*   xh       = (u16*)  (ws + alloc((size_t)N * 128 * 2));
    u16*   xl       = (u16*)  (ws + alloc((size_t)N * 128 * 2));
    u16*   meanbf   = (u16*)  (ws + alloc((size_t)N * 128 * 2));
    u16*   rhh      = (u16*)  (ws + alloc((size_t)N * 128 * 2));  // ~124 MB total

    hipMemsetAsync(cnt, 0, (size_t)N * 4, stream);
    hipMemsetAsync(bnsums, 0, 2048 * 4, stream);

    // ---- CSR build: partition edges into dense per-XCD queues, then dense passes ----
    detect_kernel<<<1, 64, 0, stream>>>(ei, flag, E);
    eccnt_kernel<<<nblk2, 256, 0, stream>>>(ei, blkcnt, flag, E);
    qscan_kernel<<<1, 256, 0, stream>>>(blkcnt, qbase, xcdstart, nblk2);
    ec2_kernel<<<nblk2, 256, 0, stream>>>(ei, qbase, qsrc, qdst, flag, E);
    hist2_kernel<<<2048, 256, 0, stream>>>(qdst, xcdstart, cnt);
    const int nb = (N + 1023) / 1024;
    scan1_kernel<<<nb, 1024, 0, stream>>>(cnt, rowstart, fill, partials, N);
    scan2_kernel<<<1, 1024, 0, stream>>>(partials, nb);
    scan3_kernel<<<nb, 1024, 0, stream>>>(rowstart, fill, partials, xcdstart, N);
    scatter2_kernel<<<2048, 256, 0, stream>>>(qsrc, qdst, xcdstart, fill, csr);

    wsplitp_kernel<<<8, 256, 0, stream>>>(Wl1, w1c, w1c + 16384);
    wsplitp_kernel<<<8, 256, 0, stream>>>(Wr1, w1c + 32768, w1c + 49152);
    wsplitp_kernel<<<8, 256, 0, stream>>>(Wl2, w2c, w2c + 16384);
    xtobf_kernel<<<(N * 64 + 255) / 256, 256, 0, stream>>>(x, xh, xl, N * 64);

    // conv1
    agg_kernel<0><<<(N + 3) / 4, 256, 0, stream>>>(xh, rowstart, csr, meanbf, nullptr);
    gemm_kernel<0><<<GGRID, 512, 0, stream>>>(meanbf, xh, xl, w1c,
                                              bl1, nullptr, rhh, bnsums);
    bnfin_kernel<<<1, 128, 0, stream>>>(bnsums, gamma, beta, bnp);
    wprep_kernel<<<128, 128, 0, stream>>>(Wr2, bl2, bnp, w2c + 32768, w2c + 49152, bias2p);
    // conv2
    agg_kernel<1><<<(N + 3) / 4, 256, 0, stream>>>(rhh, rowstart, csr, meanbf, bnp);
    gemm_kernel<1><<<GGRID, 512, 0, stream>>>(meanbf, rhh, nullptr, w2c,
                                              bias2p, outp, nullptr, nullptr);
}

// Round 7
// 505.590 us; speedup vs baseline: 1.1251x; 1.0751x over previous
//
#include <hip/hip_runtime.h>

typedef unsigned short u16;
typedef unsigned int   u32;

#define N_NODES 100000
#define NB_BKT 196    // ceil(N_NODES / 512): final dst-range buckets
#define CHUNK3 8192
#define NTILES 3125   // N_NODES / 32, exact
#define GGRID  512

typedef short frag8 __attribute__((ext_vector_type(8)));
typedef float f32x4 __attribute__((ext_vector_type(4)));
typedef float f32x2 __attribute__((ext_vector_type(2)));
typedef u32   u32x4 __attribute__((ext_vector_type(4)));

template <typename T>
__device__ __forceinline__ T ntload(const T* p) { return __builtin_nontemporal_load(p); }
template <typename T>
__device__ __forceinline__ void ntstore(T v, T* p) { __builtin_nontemporal_store(v, p); }

__device__ __forceinline__ float bf2f(u16 h) {
    union { u32 u; float f; } c; c.u = ((u32)h) << 16; return c.f;
}
__device__ __forceinline__ u16 f2bf(float f) {
    union { float f; u32 u; } c; c.f = f;
    u32 u = c.u;
    return (u16)((u + 0x7FFFu + ((u >> 16) & 1u)) >> 16);
}
__device__ __forceinline__ float2 bfx2(u32 u) {
    union { u32 u; float f; } lo, hi;
    lo.u = u << 16; hi.u = u & 0xFFFF0000u;
    return make_float2(lo.f, hi.f);
}
__device__ __forceinline__ u32 packbf(float a, float b) {
    return (u32)f2bf(a) | ((u32)f2bf(b) << 16);
}
__device__ __forceinline__ void accum8(float* av, u32x4 q) {
    float2 p0 = bfx2(q[0]), p1 = bfx2(q[1]), p2 = bfx2(q[2]), p3 = bfx2(q[3]);
    av[0] += p0.x; av[1] += p0.y; av[2] += p1.x; av[3] += p1.y;
    av[4] += p2.x; av[5] += p2.y; av[6] += p3.x; av[7] += p3.y;
}

// global -> LDS direct DMA, 16B/lane, linear LDS dest (wave-uniform base + lane*16);
// global source address is PER-LANE (m104) -> fragment-ordered staging.
__device__ __forceinline__ void gload16(const void* g, void* lds) {
    __builtin_amdgcn_global_load_lds(
        (const __attribute__((address_space(1))) unsigned int*)g,
        (__attribute__((address_space(3))) unsigned int*)lds, 16, 0, 0);
}

// LDS-only barrier: orders DS ops without draining vmcnt (keeps staging in flight)
__device__ __forceinline__ void ldsbar() {
    asm volatile("s_waitcnt lgkmcnt(0)" ::: "memory");
    __builtin_amdgcn_s_barrier();
}

union U8 { frag8 f; u16 h[8]; };

// ---------------- edge-index layout detect (int32 vs int64) ----------------
__global__ void detect_kernel(const int* __restrict__ ei, int* __restrict__ flag, int E) {
    int any = 0;
    int lim = min(2048, 2 * E);
    for (int i = 1 + 2 * (int)threadIdx.x; i < lim; i += 128) any |= ei[i];
    unsigned long long b = __ballot(any != 0);
    if (threadIdx.x == 0) *flag = (b != 0ULL) ? 1 : 0;  // 1 => int32 layout
}

// ==================== CSR build v3: ZERO device-scope atomics =====================
// R6 post-mortem: 1.6M device atomics (hist2/scatter2) execute at the device
// coherence point (per-XCD L2s not cross-coherent) -> ~51MB memory-side traffic,
// 68us scatter + ~same hist. v3: partition edges into 196 dst-range buckets
// (bucket = d>>9, 512 contiguous nodes); ONE block owns ONE bucket for hist and
// scatter -> all per-edge atomics become LDS atomics; cnt/csr are direct stores.

// ---- per-(chunk,bucket) counts: LDS hist, stored g-major for linear qscan reads --
__global__ __launch_bounds__(256) void eccnt3_kernel(const int* __restrict__ ei,
                                                     int* __restrict__ blkcnt,
                                                     const int* __restrict__ flag,
                                                     int E, int nblk) {
    __shared__ int h[NB_BKT];
    const int tid = threadIdx.x;
    for (int i = tid; i < NB_BKT; i += 256) h[i] = 0;
    __syncthreads();
    const int is32 = *flag;
    const int base = blockIdx.x * CHUNK3;
    for (int i = tid; i < CHUNK3; i += 256) {
        int e = base + i;
        if (e < E) {
            int d = is32 ? ntload(&ei[E + e]) : ntload(&ei[2 * (E + (long long)e)]);
            if ((u32)d < (u32)N_NODES) atomicAdd(&h[d >> 9], 1);
        }
    }
    __syncthreads();
    for (int i = tid; i < NB_BKT; i += 256) blkcnt[i * nblk + blockIdx.x] = h[i];
}

// ---- scan (bucket,chunk) counts -> per-chunk cursors qbase + bucket starts -------
__global__ void qscan3_kernel(const int* __restrict__ blkcnt, int* __restrict__ qbase,
                              int* __restrict__ bstart, int nblk) {
    __shared__ int lds[256];
    const int t = threadIdx.x;
    const int nseq = NB_BKT * nblk;
    const int per = (nseq + 255) / 256;
    const int j0 = t * per;
    const int j1 = min(j0 + per, nseq);
    int sum = 0;
    for (int j = j0; j < j1; ++j) sum += blkcnt[j];  // g-major: linear
    lds[t] = sum;
    __syncthreads();
    for (int off = 1; off < 256; off <<= 1) {
        int v = (t >= off) ? lds[t - off] : 0;
        __syncthreads();
        lds[t] += v;
        __syncthreads();
    }
    int run = (t > 0) ? lds[t - 1] : 0;
    int g = j0 / nblk, b = j0 - (j0 / nblk) * nblk;
    for (int j = j0; j < j1; ++j) {
        if (b == 0) bstart[g] = run;
        qbase[j] = run;
        run += blkcnt[j];
        if (++b == nblk) { b = 0; ++g; }
    }
    if (t == 255) bstart[NB_BKT] = lds[255];
}

// ---- partition edges into 196 dense bucket queues (LDS cursors, no ballots) ------
__global__ __launch_bounds__(256) void ec3_kernel(const int* __restrict__ ei,
                                                  const int* __restrict__ qbase,
                                                  int* __restrict__ qsrc,
                                                  int* __restrict__ qdst,
                                                  const int* __restrict__ flag,
                                                  int E, int nblk) {
    __shared__ int cur[NB_BKT];
    const int tid = threadIdx.x;
    for (int i = tid; i < NB_BKT; i += 256) cur[i] = qbase[i * nblk + blockIdx.x];
    __syncthreads();
    const int is32 = *flag;
    const int base = blockIdx.x * CHUNK3;
    for (int i = tid; i < CHUNK3; i += 256) {
        int e = base + i;
        if (e < E) {
            int d = is32 ? ntload(&ei[E + e]) : ntload(&ei[2 * (E + (long long)e)]);
            if ((u32)d < (u32)N_NODES) {
                int s = is32 ? ntload(&ei[e]) : ntload(&ei[2 * (long long)e]);
                if ((u32)s >= (u32)N_NODES) s = 0;
                int p = atomicAdd(&cur[d >> 9], 1);  // LDS atomic
                qdst[p] = d;
                qsrc[p] = s;
            }
        }
    }
}

// ---- per-bucket histogram: block-exclusive, LDS bins, DIRECT cnt stores ----------
__global__ __launch_bounds__(256) void hist3_kernel(const int* __restrict__ qdst,
                                                    const int* __restrict__ bstart,
                                                    int* __restrict__ cnt) {
    __shared__ int h[512];
    const int g = blockIdx.x;
    const int tid = threadIdx.x;
    h[tid] = 0; h[tid + 256] = 0;
    __syncthreads();
    const int qs = bstart[g], qe = bstart[g + 1];
    for (int i = qs + tid; i < qe; i += 256)
        atomicAdd(&h[ntload(&qdst[i]) & 511], 1);  // LDS atomic
    __syncthreads();
    const int node0 = g << 9;
    if (node0 + tid < N_NODES) cnt[node0 + tid] = h[tid];
    if (node0 + 256 + tid < N_NODES) cnt[node0 + 256 + tid] = h[tid + 256];
}

__global__ void scan1_kernel(const int* __restrict__ cnt, int* __restrict__ row,
                             int* __restrict__ fill, int* __restrict__ part, int n) {
    __shared__ int lds[1024];
    int t = threadIdx.x, g = blockIdx.x * 1024 + t;
    int v = (g < n) ? cnt[g] : 0;
    lds[t] = v;
    __syncthreads();
    for (int off = 1; off < 1024; off <<= 1) {
        int x = (t >= off) ? lds[t - off] : 0;
        __syncthreads();
        lds[t] += x;
        __syncthreads();
    }
    if (g < n) { row[g] = lds[t] - v; fill[g] = lds[t]; }  // excl / incl (= row[g+1])
    if (t == 1023) part[blockIdx.x] = lds[t];               // block total
}

__global__ void scan2_kernel(int* __restrict__ part, int nb) {
    __shared__ int lds[1024];
    int t = threadIdx.x;
    int v = (t < nb) ? part[t] : 0;
    lds[t] = v;
    __syncthreads();
    for (int off = 1; off < 1024; off <<= 1) {
        int x = (t >= off) ? lds[t - off] : 0;
        __syncthreads();
        lds[t] += x;
        __syncthreads();
    }
    if (t < nb) part[t] = lds[t] - v;
}

__global__ void scan3_kernel(int* __restrict__ row, int* __restrict__ fill,
                             const int* __restrict__ part,
                             const int* __restrict__ bstart, int n) {
    int g = blockIdx.x * 1024 + threadIdx.x;
    if (g < n) { int p = part[blockIdx.x]; row[g] += p; fill[g] += p; }
    if (g == 0) row[n] = bstart[NB_BKT];
}

// ---- per-bucket scatter: LDS cursors from fill slice, LDS atomicSub, direct csr --
__global__ __launch_bounds__(256) void scatter3_kernel(const int* __restrict__ qsrc,
                                                       const int* __restrict__ qdst,
                                                       const int* __restrict__ bstart,
                                                       const int* __restrict__ fill,
                                                       int* __restrict__ csr) {
    __shared__ int cur[512];
    const int g = blockIdx.x;
    const int tid = threadIdx.x;
    const int node0 = g << 9;
    if (node0 + tid < N_NODES) cur[tid] = fill[node0 + tid];
    if (node0 + 256 + tid < N_NODES) cur[tid + 256] = fill[node0 + 256 + tid];
    __syncthreads();
    const int qs = bstart[g], qe = bstart[g + 1];
    for (int i = qs + tid; i < qe; i += 256) {
        int d = ntload(&qdst[i]);
        int s = ntload(&qsrc[i]);
        int idx = atomicSub(&cur[d & 511], 1) - 1;  // LDS atomic
        csr[idx] = s;  // block-exclusive ~33KB range: L2-resident, evicted once
    }
}

// ---------------- weight split+permute: W(fp32) -> bf16 hi/lo planes, MFMA-frag ----
// fragment-contiguous layout: frag (ks,ft) for lane l at (ft*4+ks)*512 + l*8.
__global__ void wsplitp_kernel(const float* __restrict__ W, u16* __restrict__ hi,
                               u16* __restrict__ lo) {
    int t = blockIdx.x * 256 + threadIdx.x;  // 2048 threads: f x (ks,quad)
    if (t >= 2048) return;
    const int f = t >> 4, ks = (t >> 2) & 3, quad = t & 3;
    const int dst = ((f >> 4) * 4 + ks) * 512 + (quad * 16 + (f & 15)) * 8;
    const float* src = W + f * 128 + ks * 32 + quad * 8;
    U8 h, l;
#pragma unroll
    for (int j = 0; j < 8; ++j) {
        float v = src[j];
        u16 hh = f2bf(v);
        h.h[j] = hh;
        l.h[j] = f2bf(v - bf2f(hh));
    }
    *(frag8*)(hi + dst) = h.f;
    *(frag8*)(lo + dst) = l.f;
}

// ---------------- x -> bf16 hi + lo planes (hi: agg gather + gemm; lo: gemm) -------
__global__ void xtobf_kernel(const float* __restrict__ X, u16* __restrict__ outh,
                             u16* __restrict__ outl, int n2) {
    int i = blockIdx.x * 256 + threadIdx.x;
    if (i >= n2) return;
    f32x2 v = ntload(&((const f32x2*)X)[i]);
    u16 h0 = f2bf(v[0]), h1 = f2bf(v[1]);
    ((u32*)outh)[i] = (u32)h0 | ((u32)h1 << 16);
    ((u32*)outl)[i] = (u32)f2bf(v[0] - bf2f(h0)) | ((u32)f2bf(v[1] - bf2f(h1)) << 16);
}

// ---------------- mean aggregation over CSR (bf16 rows -> bf16 mean) ----------------
template <int MODE>
__global__ __launch_bounds__(256) void agg_kernel(
    const u16* __restrict__ X, const int* __restrict__ rowstart,
    const int* __restrict__ csr, u16* __restrict__ out,
    const float* __restrict__ bnp) {
    const int wid = (blockIdx.x * 256 + threadIdx.x) >> 6;
    const int lane = threadIdx.x & 63;
    const int g = lane >> 4;
    const int l = lane & 15;
    if (wid >= N_NODES) return;
    const int s = rowstart[wid];
    const int deg = rowstart[wid + 1] - s;
    const u32x4* Xv = (const u32x4*)X;  // row = 16 u32x4
    float av[8] = {0.f, 0.f, 0.f, 0.f, 0.f, 0.f, 0.f, 0.f};
    for (int base = 0; base < deg; base += 64) {
        const int nb = min(deg - base, 64);
        const int myidx = csr[s + base + min(lane, nb - 1)];  // one coalesced load
        int c = 0;
#pragma unroll 4
        for (; c + 4 <= nb; c += 4) {
            const int idx = __shfl(myidx, c + g, 64);
            u32x4 q = Xv[(size_t)idx * 16 + l];
            accum8(av, q);
        }
        if (c < nb) {  // tail: 1..3 neighbors
            const int idx = __shfl(myidx, min(c + g, nb - 1), 64);
            u32x4 q = Xv[(size_t)idx * 16 + l];
            if (c + g < nb) accum8(av, q);
        }
    }
#pragma unroll
    for (int j = 0; j < 8; ++j) {
        av[j] += __shfl_xor(av[j], 16, 64);
        av[j] += __shfl_xor(av[j], 32, 64);
    }
    if (g == 0) {
        const float inv = 1.0f / (float)max(deg, 1);
#pragma unroll
        for (int j = 0; j < 8; ++j) av[j] *= inv;
        if (MODE == 1) {
            if (deg > 0) {
#pragma unroll
                for (int j = 0; j < 8; ++j)
                    av[j] = av[j] * bnp[l * 8 + j] + bnp[128 + l * 8 + j];
            } else {
#pragma unroll
                for (int j = 0; j < 8; ++j) av[j] = 0.f;
            }
        }
        u32x4 o;
        o[0] = packbf(av[0], av[1]); o[1] = packbf(av[2], av[3]);
        o[2] = packbf(av[4], av[5]); o[3] = packbf(av[6], av[7]);
        ((u32x4*)out)[(size_t)wid * 16 + l] = o;  // cached: consumed by gemm
    }
}

// ---------------- fused GEMM v6: reg weights (no spill) + frag-ordered LDS A -------
// (unchanged from round 6 — gemm is no longer the top dispatch)
template <int GM>
__global__ __launch_bounds__(512, 2) void gemm_kernel(
    const u16* __restrict__ A1bf, const u16* __restrict__ A2h_,
    const u16* __restrict__ A2l_, const u16* __restrict__ Wc,
    const float* __restrict__ bias, float* __restrict__ outf,
    u16* __restrict__ outb, float* __restrict__ bnsums) {
    constexpr int NREG = (GM == 0) ? 3 : 2;       // staging regions (A1,A2h[,A2l])
    constexpr int TB = NREG * 8192;               // bytes per buffer
    constexpr int OB = (GM == 0) ? 8192 : 16384;  // out-bounce bytes
    __shared__ __align__(16) char bufs[2][TB];
    __shared__ __align__(16) char outbuf[OB];
    __shared__ float ssrow2[32][8];  // [row][wave] L2-norm partials
    const int tid = threadIdx.x;
    const int lane = tid & 63;
    const int wv = tid >> 6;      // 0..7 = output-feature slice
    const int col = lane & 15;
    const int quad = lane >> 4;

    auto stage = [&](char* buf, int trow0) {
        // chunk m = rgn*8 + c; c=(mt<<2)|ks; frag-ordered: LDS m*1KB + lane*16
        // global: row (trow0 + mt*16 + col)*256B + ks*64 + quad*16 (full 64B lines)
#pragma unroll
        for (int j = 0; j < NREG; ++j) {
            const int m = j * 8 + wv;
            const int c = m & 7;
            const int rgn = m >> 3;
            const u16* srcp = (rgn == 0) ? A1bf : (rgn == 1) ? A2h_ : A2l_;
            gload16((const char*)srcp +
                        (size_t)(trow0 + ((c >> 2) << 4) + (lane & 15)) * 256 +
                        ((c & 3) << 6) + ((lane >> 4) << 4),
                    buf + m * 1024);
        }
    };

    // ---- weights: this wave's ft slice, all planes/ksteps, register-resident ----
    int cur = 0;
    stage(bufs[0], blockIdx.x * 32);
    frag8 wlh[4], wll[4], wrh[4], wrl[4];
#pragma unroll
    for (int ks = 0; ks < 4; ++ks) {
        const int wo = (wv * 4 + ks) * 512 + lane * 8;
        wlh[ks] = *(const frag8*)(Wc + wo);
        wll[ks] = *(const frag8*)(Wc + 16384 + wo);
        wrh[ks] = *(const frag8*)(Wc + 32768 + wo);
        wrl[ks] = *(const frag8*)(Wc + 49152 + wo);
    }
    const float bsv = bias[wv * 16 + col];
    float bn1 = 0.f, bn2 = 0.f;

    for (int t = blockIdx.x; t < NTILES; t += GGRID) {
        __syncthreads();  // drains vmcnt: buf[cur] fully staged; prev-tile LDS done
        const int tn = t + GGRID;
        if (tn < NTILES) stage(bufs[cur ^ 1], tn * 32);

        // ---- k-loop: lane-contiguous LDS fragment reads + MFMA, zero VALU ----
        f32x4 acc[2];
        acc[0] = (f32x4){0.f, 0.f, 0.f, 0.f};
        acc[1] = (f32x4){0.f, 0.f, 0.f, 0.f};
        char* buf = bufs[cur];
#pragma unroll
        for (int ks = 0; ks < 4; ++ks) {
            frag8 a1[2], a2h[2], a2l[2];
#pragma unroll
            for (int mt = 0; mt < 2; ++mt) {
                const int fo = ((mt << 2) + ks) * 1024 + lane * 16;
                a1[mt] = *(const frag8*)(buf + fo);
                a2h[mt] = *(const frag8*)(buf + 8192 + fo);
                if (GM == 0) a2l[mt] = *(const frag8*)(buf + 16384 + fo);
            }
#pragma unroll
            for (int mt = 0; mt < 2; ++mt) {
                acc[mt] = __builtin_amdgcn_mfma_f32_16x16x32_bf16(a1[mt], wlh[ks], acc[mt], 0, 0, 0);
                acc[mt] = __builtin_amdgcn_mfma_f32_16x16x32_bf16(a1[mt], wll[ks], acc[mt], 0, 0, 0);
                acc[mt] = __builtin_amdgcn_mfma_f32_16x16x32_bf16(a2h[mt], wrh[ks], acc[mt], 0, 0, 0);
                if (GM == 0)
                    acc[mt] = __builtin_amdgcn_mfma_f32_16x16x32_bf16(a2l[mt], wrh[ks], acc[mt], 0, 0, 0);
                acc[mt] = __builtin_amdgcn_mfma_f32_16x16x32_bf16(a2h[mt], wrl[ks], acc[mt], 0, 0, 0);
            }
        }

        // ---- epilogue: bias, cross-wave row-norm, LDS-bounce store, BN accum ----
        float tv[2][4], sq[2][4];
#pragma unroll
        for (int mt = 0; mt < 2; ++mt)
#pragma unroll
            for (int r = 0; r < 4; ++r) {
                float v = acc[mt][r] + bsv;
                tv[mt][r] = v;
                sq[mt][r] = v * v;
            }
#pragma unroll
        for (int m = 1; m <= 8; m <<= 1)
#pragma unroll
            for (int mt = 0; mt < 2; ++mt)
#pragma unroll
                for (int r = 0; r < 4; ++r) sq[mt][r] += __shfl_xor(sq[mt][r], m, 64);
        if (col == 0) {
#pragma unroll
            for (int mt = 0; mt < 2; ++mt)
#pragma unroll
                for (int r = 0; r < 4; ++r)
                    ssrow2[mt * 16 + quad * 4 + r][wv] = sq[mt][r];
        }
        ldsbar();  // partials visible; staging stays in flight

#pragma unroll
        for (int mt = 0; mt < 2; ++mt)
#pragma unroll
            for (int r = 0; r < 4; ++r) {
                const int rw = mt * 16 + quad * 4 + r;
                f32x4 p0 = *(const f32x4*)&ssrow2[rw][0];
                f32x4 p4 = *(const f32x4*)&ssrow2[rw][4];
                float ss = ((p0[0] + p0[1]) + (p0[2] + p0[3])) +
                           ((p4[0] + p4[1]) + (p4[2] + p4[3]));
                float inv = 1.0f / fmaxf(sqrtf(ss), 1e-12f);
                float o = tv[mt][r] * inv;
                if (GM == 0) {
                    o = fmaxf(o, 0.f);
                    bn1 += o; bn2 += o * o;
                    float po = __shfl_xor(o, 1, 64);
                    if (!(lane & 1))
                        ((u32*)outbuf)[rw * 64 + wv * 8 + (col >> 1)] = packbf(o, po);
                } else {
                    ((float*)outbuf)[rw * 128 + wv * 16 + col] = o;
                }
            }
        ldsbar();  // out-bounce complete

        // ---- linear full-line global write ----
        const size_t rowbase = (size_t)t * 32;
        if (GM == 0) {
            u32x4 v = *(const u32x4*)(outbuf + tid * 16);
            *(u32x4*)((char*)outb + rowbase * 256 + tid * 16) = v;  // cached: rhh reused
        } else {
            f32x4 v0 = *(const f32x4*)(outbuf + tid * 32);
            f32x4 v1 = *(const f32x4*)(outbuf + tid * 32 + 16);
            ntstore(v0, (f32x4*)((char*)outf + rowbase * 512 + tid * 32));
            ntstore(v1, (f32x4*)((char*)outf + rowbase * 512 + tid * 32 + 16));
        }
        cur ^= 1;
    }

    if (GM == 0) {
        bn1 += __shfl_xor(bn1, 16, 64); bn1 += __shfl_xor(bn1, 32, 64);
        bn2 += __shfl_xor(bn2, 16, 64); bn2 += __shfl_xor(bn2, 32, 64);
        if (lane < 16) {  // quad==0 lanes hold per-feature totals
            const int slot = (blockIdx.x & 7) * 256;
            atomicAdd(&bnsums[slot + wv * 16 + lane], bn1);
            atomicAdd(&bnsums[slot + 128 + wv * 16 + lane], bn2);
        }
    }
}

// ---------------- BN finalize: scale/shift from 8-slot sums ----------------
__global__ void bnfin_kernel(const float* __restrict__ sums, const float* __restrict__ gamma,
                             const float* __restrict__ beta, float* __restrict__ bnp) {
    int f = threadIdx.x;
    if (f >= 128) return;
    float s1 = 0.f, s2 = 0.f;
#pragma unroll
    for (int k = 0; k < 8; ++k) {
        s1 += sums[k * 256 + f];
        s2 += sums[k * 256 + 128 + f];
    }
    const float invN = 1.0f / (float)N_NODES;
    float mu = s1 * invN;
    float var = s2 * invN - mu * mu;
    float sc = gamma[f] * rsqrtf(fmaxf(var, 0.f) + 1e-5f);
    bnp[f] = sc;
    bnp[128 + f] = beta[f] - mu * sc;
}

// ---------------- layer-2 weight prep: Wr2' = s .* Wr2 (split+permute), bias2' ----
__global__ void wprep_kernel(const float* __restrict__ Wr2, const float* __restrict__ bl2,
                             const float* __restrict__ bnp, u16* __restrict__ wh,
                             u16* __restrict__ wl, float* __restrict__ bias2p) {
    __shared__ float p[2];
    const int f = blockIdx.x;
    const int k = threadIdx.x;  // 128 threads
    float w = Wr2[f * 128 + k];
    float contrib = w * bnp[128 + k];
    float v = w * bnp[k];
    u16 h = f2bf(v);
    const int ks = k >> 5, quad = (k >> 3) & 3, j = k & 7;
    const int dst = ((f >> 4) * 4 + ks) * 512 + (quad * 16 + (f & 15)) * 8 + j;
    wh[dst] = h;
    wl[dst] = f2bf(v - bf2f(h));
#pragma unroll
    for (int m = 1; m <= 32; m <<= 1) contrib += __shfl_xor(contrib, m, 64);
    if ((k & 63) == 0) p[k >> 6] = contrib;
    __syncthreads();
    if (k == 0) bias2p[f] = bl2[f] + p[0] + p[1];
}

extern "C" void kernel_launch(void* const* d_in, const int* in_sizes, int n_in,
                              void* d_out, int out_size, void* d_ws, size_t ws_size,
                              hipStream_t stream) {
    const int N = N_NODES;
    const int E = in_sizes[1] / 2;
    const int nblk3 = (E + CHUNK3 - 1) / CHUNK3;

    const float* x     = (const float*)d_in[0];
    const int*   ei    = (const int*)d_in[1];
    const float* Wl1   = (const float*)d_in[2];
    const float* bl1   = (const float*)d_in[3];
    const float* Wr1   = (const float*)d_in[4];
    const float* gamma = (const float*)d_in[5];
    const float* beta  = (const float*)d_in[6];
    const float* Wl2   = (const float*)d_in[7];
    const float* bl2   = (const float*)d_in[8];
    const float* Wr2   = (const float*)d_in[9];
    float* outp = (float*)d_out;

    char* ws = (char*)d_ws;
    size_t off = 0;
    auto alloc = [&](size_t b) { size_t r = off; off += (b + 255) & ~(size_t)255; return r; };
    int*   flag     = (int*)  (ws + alloc(4));
    int*   cnt      = (int*)  (ws + alloc((size_t)N * 4));
    int*   rowstart = (int*)  (ws + alloc((size_t)(N + 1) * 4));
    int*   fill     = (int*)  (ws + alloc((size_t)N * 4));
    int*   partials = (int*)  (ws + alloc(4096));
    int*   bstart   = (int*)  (ws + alloc((NB_BKT + 1) * 4));
    int*   blkcnt   = (int*)  (ws + alloc((size_t)nblk3 * NB_BKT * 4));
    int*   qbase    = (int*)  (ws + alloc((size_t)nblk3 * NB_BKT * 4));
    int*   csr      = (int*)  (ws + alloc((size_t)E * 4));
    int*   qsrc     = (int*)  (ws + alloc((size_t)E * 4));
    int*   qdst     = (int*)  (ws + alloc((size_t)E * 4));
    float* bnsums   = (float*)(ws + alloc(2048 * 4));   // 8 slots x 256
    float* bnp      = (float*)(ws + alloc(256 * 4));
    float* bias2p   = (float*)(ws + alloc(128 * 4));
    u16*   w1c      = (u16*)  (ws + alloc(65536 * 2));  // 4 planes: lh,ll,rh,rl
    u16*   w2c      = (u16*)  (ws + alloc(65536 * 2));  // 4 planes: lh,ll,rsh,rsl
    u16*   xh       = (u16*)  (ws + alloc((size_t)N * 128 * 2));
    u16*   xl       = (u16*)  (ws + alloc((size_t)N * 128 * 2));
    u16*   meanbf   = (u16*)  (ws + alloc((size_t)N * 128 * 2));
    u16*   rhh      = (u16*)  (ws + alloc((size_t)N * 128 * 2));  // ~125 MB total

    hipMemsetAsync(bnsums, 0, 2048 * 4, stream);  // cnt memset no longer needed

    // ---- CSR build v3: bucket partition, block-exclusive hist/scatter, 0 atomics --
    detect_kernel<<<1, 64, 0, stream>>>(ei, flag, E);
    eccnt3_kernel<<<nblk3, 256, 0, stream>>>(ei, blkcnt, flag, E, nblk3);
    qscan3_kernel<<<1, 256, 0, stream>>>(blkcnt, qbase, bstart, nblk3);
    ec3_kernel<<<nblk3, 256, 0, stream>>>(ei, qbase, qsrc, qdst, flag, E, nblk3);
    hist3_kernel<<<NB_BKT, 256, 0, stream>>>(qdst, bstart, cnt);
    const int nb = (N + 1023) / 1024;
    scan1_kernel<<<nb, 1024, 0, stream>>>(cnt, rowstart, fill, partials, N);
    scan2_kernel<<<1, 1024, 0, stream>>>(partials, nb);
    scan3_kernel<<<nb, 1024, 0, stream>>>(rowstart, fill, partials, bstart, N);
    scatter3_kernel<<<NB_BKT, 256, 0, stream>>>(qsrc, qdst, bstart, fill, csr);

    wsplitp_kernel<<<8, 256, 0, stream>>>(Wl1, w1c, w1c + 16384);
    wsplitp_kernel<<<8, 256, 0, stream>>>(Wr1, w1c + 32768, w1c + 49152);
    wsplitp_kernel<<<8, 256, 0, stream>>>(Wl2, w2c, w2c + 16384);
    xtobf_kernel<<<(N * 64 + 255) / 256, 256, 0, stream>>>(x, xh, xl, N * 64);

    // conv1
    agg_kernel<0><<<(N + 3) / 4, 256, 0, stream>>>(xh, rowstart, csr, meanbf, nullptr);
    gemm_kernel<0><<<GGRID, 512, 0, stream>>>(meanbf, xh, xl, w1c,
                                              bl1, nullptr, rhh, bnsums);
    bnfin_kernel<<<1, 128, 0, stream>>>(bnsums, gamma, beta, bnp);
    wprep_kernel<<<128, 128, 0, stream>>>(Wr2, bl2, bnp, w2c + 32768, w2c + 49152, bias2p);
    // conv2
    agg_kernel<1><<<(N + 3) / 4, 256, 0, stream>>>(rhh, rowstart, csr, meanbf, bnp);
    gemm_kernel<1><<<GGRID, 512, 0, stream>>>(meanbf, rhh, nullptr, w2c,
                                              bias2p, outp, nullptr, nullptr);
}

// Round 8
// 448.780 us; speedup vs baseline: 1.2675x; 1.1266x over previous
//
#include <hip/hip_runtime.h>

typedef unsigned short u16;
typedef unsigned int   u32;

#define N_NODES 100000
#define NB_BKT 196    // ceil(N_NODES / 512): final dst-range buckets
#define CHUNK3 8192
#define NTILES 3125   // N_NODES / 32, exact
#define GGRID  512

typedef short frag8 __attribute__((ext_vector_type(8)));
typedef float f32x4 __attribute__((ext_vector_type(4)));
typedef float f32x2 __attribute__((ext_vector_type(2)));
typedef u32   u32x4 __attribute__((ext_vector_type(4)));

template <typename T>
__device__ __forceinline__ T ntload(const T* p) { return __builtin_nontemporal_load(p); }
template <typename T>
__device__ __forceinline__ void ntstore(T v, T* p) { __builtin_nontemporal_store(v, p); }

__device__ __forceinline__ float bf2f(u16 h) {
    union { u32 u; float f; } c; c.u = ((u32)h) << 16; return c.f;
}
__device__ __forceinline__ u16 f2bf(float f) {
    union { float f; u32 u; } c; c.f = f;
    u32 u = c.u;
    return (u16)((u + 0x7FFFu + ((u >> 16) & 1u)) >> 16);
}
__device__ __forceinline__ float2 bfx2(u32 u) {
    union { u32 u; float f; } lo, hi;
    lo.u = u << 16; hi.u = u & 0xFFFF0000u;
    return make_float2(lo.f, hi.f);
}
__device__ __forceinline__ u32 packbf(float a, float b) {
    return (u32)f2bf(a) | ((u32)f2bf(b) << 16);
}
__device__ __forceinline__ void accum8(float* av, u32x4 q) {
    float2 p0 = bfx2(q[0]), p1 = bfx2(q[1]), p2 = bfx2(q[2]), p3 = bfx2(q[3]);
    av[0] += p0.x; av[1] += p0.y; av[2] += p1.x; av[3] += p1.y;
    av[4] += p2.x; av[5] += p2.y; av[6] += p3.x; av[7] += p3.y;
}

// global -> LDS direct DMA, 16B/lane, linear LDS dest (wave-uniform base + lane*16);
// global source address is PER-LANE (m104) -> fragment-ordered staging.
__device__ __forceinline__ void gload16(const void* g, void* lds) {
    __builtin_amdgcn_global_load_lds(
        (const __attribute__((address_space(1))) unsigned int*)g,
        (__attribute__((address_space(3))) unsigned int*)lds, 16, 0, 0);
}

// LDS-only barrier: orders DS ops without draining vmcnt (keeps staging in flight)
__device__ __forceinline__ void ldsbar() {
    asm volatile("s_waitcnt lgkmcnt(0)" ::: "memory");
    __builtin_amdgcn_s_barrier();
}

union U8 { frag8 f; u16 h[8]; };

// ---------------- edge-index layout detect (int32 vs int64) ----------------
__global__ void detect_kernel(const int* __restrict__ ei, int* __restrict__ flag, int E) {
    int any = 0;
    int lim = min(2048, 2 * E);
    for (int i = 1 + 2 * (int)threadIdx.x; i < lim; i += 128) any |= ei[i];
    unsigned long long b = __ballot(any != 0);
    if (threadIdx.x == 0) *flag = (b != 0ULL) ? 1 : 0;  // 1 => int32 layout
}

// ==================== CSR build v3: ZERO device-scope atomics =====================
// Edges partitioned into 196 dst-range buckets (bucket = d>>9); ONE block owns ONE
// bucket for hist and scatter -> per-edge atomics are LDS-only; cnt/csr direct.

// ---- per-(chunk,bucket) counts: LDS hist, stored g-major for linear scans --------
__global__ __launch_bounds__(256) void eccnt3_kernel(const int* __restrict__ ei,
                                                     int* __restrict__ blkcnt,
                                                     const int* __restrict__ flag,
                                                     int E, int nblk) {
    __shared__ int h[NB_BKT];
    const int tid = threadIdx.x;
    for (int i = tid; i < NB_BKT; i += 256) h[i] = 0;
    __syncthreads();
    const int is32 = *flag;
    const int base = blockIdx.x * CHUNK3;
    for (int i = tid; i < CHUNK3; i += 256) {
        int e = base + i;
        if (e < E) {
            int d = is32 ? ntload(&ei[E + e]) : ntload(&ei[2 * (E + (long long)e)]);
            if ((u32)d < (u32)N_NODES) atomicAdd(&h[d >> 9], 1);
        }
    }
    __syncthreads();
    for (int i = tid; i < NB_BKT; i += 256) blkcnt[i * nblk + blockIdx.x] = h[i];
}

// ---- R7 post-mortem: single-block qscan3 was a 65us serial-latency chain (256
// threads x ~151 DEPENDENT L2 loads). v4: hierarchical parallel scan, 3 launches.
// qscanA: one block per bucket scans its nblk per-chunk counts (within-bucket
// exclusive prefix -> qbase, total -> btot). All coalesced, LDS Hillis-Steele.
__global__ __launch_bounds__(256) void qscanA_kernel(const int* __restrict__ blkcnt,
                                                     int* __restrict__ qbase,
                                                     int* __restrict__ btot, int nblk) {
    __shared__ int lds[256];
    const int g = blockIdx.x;
    const int t = threadIdx.x;
    int carry = 0;
    for (int base = 0; base < nblk; base += 256) {
        const int idx = base + t;
        int v = (idx < nblk) ? blkcnt[g * nblk + idx] : 0;
        lds[t] = v;
        __syncthreads();
        for (int off = 1; off < 256; off <<= 1) {
            int x = (t >= off) ? lds[t - off] : 0;
            __syncthreads();
            lds[t] += x;
            __syncthreads();
        }
        if (idx < nblk) qbase[g * nblk + idx] = carry + lds[t] - v;  // excl prefix
        carry += lds[255];
        __syncthreads();
    }
    if (t == 0) btot[g] = carry;
}

// qscanB: single small scan of the 196 bucket totals -> bstart (exclusive).
__global__ void qscanB_kernel(const int* __restrict__ btot, int* __restrict__ bstart) {
    __shared__ int lds[256];
    const int t = threadIdx.x;
    int v = (t < NB_BKT) ? btot[t] : 0;
    lds[t] = v;
    __syncthreads();
    for (int off = 1; off < 256; off <<= 1) {
        int x = (t >= off) ? lds[t - off] : 0;
        __syncthreads();
        lds[t] += x;
        __syncthreads();
    }
    if (t < NB_BKT) bstart[t] = lds[t] - v;
    if (t == 255) bstart[NB_BKT] = lds[255];
}

// ---- partition edges into 196 dense bucket queues (LDS cursors, no ballots) ------
__global__ __launch_bounds__(256) void ec3_kernel(const int* __restrict__ ei,
                                                  const int* __restrict__ qbase,
                                                  const int* __restrict__ bstart,
                                                  int* __restrict__ qsrc,
                                                  int* __restrict__ qdst,
                                                  const int* __restrict__ flag,
                                                  int E, int nblk) {
    __shared__ int cur[NB_BKT];
    const int tid = threadIdx.x;
    for (int i = tid; i < NB_BKT; i += 256)
        cur[i] = qbase[i * nblk + blockIdx.x] + bstart[i];
    __syncthreads();
    const int is32 = *flag;
    const int base = blockIdx.x * CHUNK3;
    for (int i = tid; i < CHUNK3; i += 256) {
        int e = base + i;
        if (e < E) {
            int d = is32 ? ntload(&ei[E + e]) : ntload(&ei[2 * (E + (long long)e)]);
            if ((u32)d < (u32)N_NODES) {
                int s = is32 ? ntload(&ei[e]) : ntload(&ei[2 * (long long)e]);
                if ((u32)s >= (u32)N_NODES) s = 0;
                int p = atomicAdd(&cur[d >> 9], 1);  // LDS atomic
                qdst[p] = d;
                qsrc[p] = s;
            }
        }
    }
}

// ---- per-bucket histogram: block-exclusive, LDS bins, DIRECT cnt stores ----------
__global__ __launch_bounds__(256) void hist3_kernel(const int* __restrict__ qdst,
                                                    const int* __restrict__ bstart,
                                                    int* __restrict__ cnt) {
    __shared__ int h[512];
    const int g = blockIdx.x;
    const int tid = threadIdx.x;
    h[tid] = 0; h[tid + 256] = 0;
    __syncthreads();
    const int qs = bstart[g], qe = bstart[g + 1];
    for (int i = qs + tid; i < qe; i += 256)
        atomicAdd(&h[ntload(&qdst[i]) & 511], 1);  // LDS atomic
    __syncthreads();
    const int node0 = g << 9;
    if (node0 + tid < N_NODES) cnt[node0 + tid] = h[tid];
    if (node0 + 256 + tid < N_NODES) cnt[node0 + 256 + tid] = h[tid + 256];
}

__global__ void scan1_kernel(const int* __restrict__ cnt, int* __restrict__ row,
                             int* __restrict__ fill, int* __restrict__ part, int n) {
    __shared__ int lds[1024];
    int t = threadIdx.x, g = blockIdx.x * 1024 + t;
    int v = (g < n) ? cnt[g] : 0;
    lds[t] = v;
    __syncthreads();
    for (int off = 1; off < 1024; off <<= 1) {
        int x = (t >= off) ? lds[t - off] : 0;
        __syncthreads();
        lds[t] += x;
        __syncthreads();
    }
    if (g < n) { row[g] = lds[t] - v; fill[g] = lds[t]; }  // excl / incl (= row[g+1])
    if (t == 1023) part[blockIdx.x] = lds[t];               // block total
}

__global__ void scan2_kernel(int* __restrict__ part, int nb) {
    __shared__ int lds[1024];
    int t = threadIdx.x;
    int v = (t < nb) ? part[t] : 0;
    lds[t] = v;
    __syncthreads();
    for (int off = 1; off < 1024; off <<= 1) {
        int x = (t >= off) ? lds[t - off] : 0;
        __syncthreads();
        lds[t] += x;
        __syncthreads();
    }
    if (t < nb) part[t] = lds[t] - v;
}

__global__ void scan3_kernel(int* __restrict__ row, int* __restrict__ fill,
                             const int* __restrict__ part,
                             const int* __restrict__ bstart, int n) {
    int g = blockIdx.x * 1024 + threadIdx.x;
    if (g < n) { int p = part[blockIdx.x]; row[g] += p; fill[g] += p; }
    if (g == 0) row[n] = bstart[NB_BKT];
}

// ---- per-bucket scatter: LDS cursors from fill slice, LDS atomicSub, direct csr --
__global__ __launch_bounds__(256) void scatter3_kernel(const int* __restrict__ qsrc,
                                                       const int* __restrict__ qdst,
                                                       const int* __restrict__ bstart,
                                                       const int* __restrict__ fill,
                                                       int* __restrict__ csr) {
    __shared__ int cur[512];
    const int g = blockIdx.x;
    const int tid = threadIdx.x;
    const int node0 = g << 9;
    if (node0 + tid < N_NODES) cur[tid] = fill[node0 + tid];
    if (node0 + 256 + tid < N_NODES) cur[tid + 256] = fill[node0 + 256 + tid];
    __syncthreads();
    const int qs = bstart[g], qe = bstart[g + 1];
    for (int i = qs + tid; i < qe; i += 256) {
        int d = ntload(&qdst[i]);
        int s = ntload(&qsrc[i]);
        int idx = atomicSub(&cur[d & 511], 1) - 1;  // LDS atomic
        csr[idx] = s;  // block-exclusive ~33KB range: L2-resident, evicted once
    }
}

// ---------------- weight split+permute: W(fp32) -> bf16 hi/lo planes, MFMA-frag ----
// fragment-contiguous layout: frag (ks,ft) for lane l at (ft*4+ks)*512 + l*8.
__global__ void wsplitp_kernel(const float* __restrict__ W, u16* __restrict__ hi,
                               u16* __restrict__ lo) {
    int t = blockIdx.x * 256 + threadIdx.x;  // 2048 threads: f x (ks,quad)
    if (t >= 2048) return;
    const int f = t >> 4, ks = (t >> 2) & 3, quad = t & 3;
    const int dst = ((f >> 4) * 4 + ks) * 512 + (quad * 16 + (f & 15)) * 8;
    const float* src = W + f * 128 + ks * 32 + quad * 8;
    U8 h, l;
#pragma unroll
    for (int j = 0; j < 8; ++j) {
        float v = src[j];
        u16 hh = f2bf(v);
        h.h[j] = hh;
        l.h[j] = f2bf(v - bf2f(hh));
    }
    *(frag8*)(hi + dst) = h.f;
    *(frag8*)(lo + dst) = l.f;
}

// ---------------- x -> bf16 hi + lo planes (hi: agg gather + gemm; lo: gemm) -------
__global__ void xtobf_kernel(const float* __restrict__ X, u16* __restrict__ outh,
                             u16* __restrict__ outl, int n2) {
    int i = blockIdx.x * 256 + threadIdx.x;
    if (i >= n2) return;
    f32x2 v = ntload(&((const f32x2*)X)[i]);
    u16 h0 = f2bf(v[0]), h1 = f2bf(v[1]);
    ((u32*)outh)[i] = (u32)h0 | ((u32)h1 << 16);
    ((u32*)outl)[i] = (u32)f2bf(v[0] - bf2f(h0)) | ((u32)f2bf(v[1] - bf2f(h1)) << 16);
}

// ---------------- mean aggregation over CSR (bf16 rows -> bf16 mean) ----------------
template <int MODE>
__global__ __launch_bounds__(256) void agg_kernel(
    const u16* __restrict__ X, const int* __restrict__ rowstart,
    const int* __restrict__ csr, u16* __restrict__ out,
    const float* __restrict__ bnp) {
    const int wid = (blockIdx.x * 256 + threadIdx.x) >> 6;
    const int lane = threadIdx.x & 63;
    const int g = lane >> 4;
    const int l = lane & 15;
    if (wid >= N_NODES) return;
    const int s = rowstart[wid];
    const int deg = rowstart[wid + 1] - s;
    const u32x4* Xv = (const u32x4*)X;  // row = 16 u32x4
    float av[8] = {0.f, 0.f, 0.f, 0.f, 0.f, 0.f, 0.f, 0.f};
    for (int base = 0; base < deg; base += 64) {
        const int nb = min(deg - base, 64);
        const int myidx = csr[s + base + min(lane, nb - 1)];  // one coalesced load
        int c = 0;
#pragma unroll 4
        for (; c + 4 <= nb; c += 4) {
            const int idx = __shfl(myidx, c + g, 64);
            u32x4 q = Xv[(size_t)idx * 16 + l];
            accum8(av, q);
        }
        if (c < nb) {  // tail: 1..3 neighbors
            const int idx = __shfl(myidx, min(c + g, nb - 1), 64);
            u32x4 q = Xv[(size_t)idx * 16 + l];
            if (c + g < nb) accum8(av, q);
        }
    }
#pragma unroll
    for (int j = 0; j < 8; ++j) {
        av[j] += __shfl_xor(av[j], 16, 64);
        av[j] += __shfl_xor(av[j], 32, 64);
    }
    if (g == 0) {
        const float inv = 1.0f / (float)max(deg, 1);
#pragma unroll
        for (int j = 0; j < 8; ++j) av[j] *= inv;
        if (MODE == 1) {
            if (deg > 0) {
#pragma unroll
                for (int j = 0; j < 8; ++j)
                    av[j] = av[j] * bnp[l * 8 + j] + bnp[128 + l * 8 + j];
            } else {
#pragma unroll
                for (int j = 0; j < 8; ++j) av[j] = 0.f;
            }
        }
        u32x4 o;
        o[0] = packbf(av[0], av[1]); o[1] = packbf(av[2], av[3]);
        o[2] = packbf(av[4], av[5]); o[3] = packbf(av[6], av[7]);
        ((u32x4*)out)[(size_t)wid * 16 + l] = o;  // cached: consumed by gemm
    }
}

// ---------------- fused GEMM v6: reg weights (no spill) + frag-ordered LDS A -------
// (unchanged — gemm is no longer the top dispatch)
template <int GM>
__global__ __launch_bounds__(512, 2) void gemm_kernel(
    const u16* __restrict__ A1bf, const u16* __restrict__ A2h_,
    const u16* __restrict__ A2l_, const u16* __restrict__ Wc,
    const float* __restrict__ bias, float* __restrict__ outf,
    u16* __restrict__ outb, float* __restrict__ bnsums) {
    constexpr int NREG = (GM == 0) ? 3 : 2;       // staging regions (A1,A2h[,A2l])
    constexpr int TB = NREG * 8192;               // bytes per buffer
    constexpr int OB = (GM == 0) ? 8192 : 16384;  // out-bounce bytes
    __shared__ __align__(16) char bufs[2][TB];
    __shared__ __align__(16) char outbuf[OB];
    __shared__ float ssrow2[32][8];  // [row][wave] L2-norm partials
    const int tid = threadIdx.x;
    const int lane = tid & 63;
    const int wv = tid >> 6;      // 0..7 = output-feature slice
    const int col = lane & 15;
    const int quad = lane >> 4;

    auto stage = [&](char* buf, int trow0) {
        // chunk m = rgn*8 + c; c=(mt<<2)|ks; frag-ordered: LDS m*1KB + lane*16
        // global: row (trow0 + mt*16 + col)*256B + ks*64 + quad*16 (full 64B lines)
#pragma unroll
        for (int j = 0; j < NREG; ++j) {
            const int m = j * 8 + wv;
            const int c = m & 7;
            const int rgn = m >> 3;
            const u16* srcp = (rgn == 0) ? A1bf : (rgn == 1) ? A2h_ : A2l_;
            gload16((const char*)srcp +
                        (size_t)(trow0 + ((c >> 2) << 4) + (lane & 15)) * 256 +
                        ((c & 3) << 6) + ((lane >> 4) << 4),
                    buf + m * 1024);
        }
    };

    // ---- weights: this wave's ft slice, all planes/ksteps, register-resident ----
    int cur = 0;
    stage(bufs[0], blockIdx.x * 32);
    frag8 wlh[4], wll[4], wrh[4], wrl[4];
#pragma unroll
    for (int ks = 0; ks < 4; ++ks) {
        const int wo = (wv * 4 + ks) * 512 + lane * 8;
        wlh[ks] = *(const frag8*)(Wc + wo);
        wll[ks] = *(const frag8*)(Wc + 16384 + wo);
        wrh[ks] = *(const frag8*)(Wc + 32768 + wo);
        wrl[ks] = *(const frag8*)(Wc + 49152 + wo);
    }
    const float bsv = bias[wv * 16 + col];
    float bn1 = 0.f, bn2 = 0.f;

    for (int t = blockIdx.x; t < NTILES; t += GGRID) {
        __syncthreads();  // drains vmcnt: buf[cur] fully staged; prev-tile LDS done
        const int tn = t + GGRID;
        if (tn < NTILES) stage(bufs[cur ^ 1], tn * 32);

        // ---- k-loop: lane-contiguous LDS fragment reads + MFMA, zero VALU ----
        f32x4 acc[2];
        acc[0] = (f32x4){0.f, 0.f, 0.f, 0.f};
        acc[1] = (f32x4){0.f, 0.f, 0.f, 0.f};
        char* buf = bufs[cur];
#pragma unroll
        for (int ks = 0; ks < 4; ++ks) {
            frag8 a1[2], a2h[2], a2l[2];
#pragma unroll
            for (int mt = 0; mt < 2; ++mt) {
                const int fo = ((mt << 2) + ks) * 1024 + lane * 16;
                a1[mt] = *(const frag8*)(buf + fo);
                a2h[mt] = *(const frag8*)(buf + 8192 + fo);
                if (GM == 0) a2l[mt] = *(const frag8*)(buf + 16384 + fo);
            }
#pragma unroll
            for (int mt = 0; mt < 2; ++mt) {
                acc[mt] = __builtin_amdgcn_mfma_f32_16x16x32_bf16(a1[mt], wlh[ks], acc[mt], 0, 0, 0);
                acc[mt] = __builtin_amdgcn_mfma_f32_16x16x32_bf16(a1[mt], wll[ks], acc[mt], 0, 0, 0);
                acc[mt] = __builtin_amdgcn_mfma_f32_16x16x32_bf16(a2h[mt], wrh[ks], acc[mt], 0, 0, 0);
                if (GM == 0)
                    acc[mt] = __builtin_amdgcn_mfma_f32_16x16x32_bf16(a2l[mt], wrh[ks], acc[mt], 0, 0, 0);
                acc[mt] = __builtin_amdgcn_mfma_f32_16x16x32_bf16(a2h[mt], wrl[ks], acc[mt], 0, 0, 0);
            }
        }

        // ---- epilogue: bias, cross-wave row-norm, LDS-bounce store, BN accum ----
        float tv[2][4], sq[2][4];
#pragma unroll
        for (int mt = 0; mt < 2; ++mt)
#pragma unroll
            for (int r = 0; r < 4; ++r) {
                float v = acc[mt][r] + bsv;
                tv[mt][r] = v;
                sq[mt][r] = v * v;
            }
#pragma unroll
        for (int m = 1; m <= 8; m <<= 1)
#pragma unroll
            for (int mt = 0; mt < 2; ++mt)
#pragma unroll
                for (int r = 0; r < 4; ++r) sq[mt][r] += __shfl_xor(sq[mt][r], m, 64);
        if (col == 0) {
#pragma unroll
            for (int mt = 0; mt < 2; ++mt)
#pragma unroll
                for (int r = 0; r < 4; ++r)
                    ssrow2[mt * 16 + quad * 4 + r][wv] = sq[mt][r];
        }
        ldsbar();  // partials visible; staging stays in flight

#pragma unroll
        for (int mt = 0; mt < 2; ++mt)
#pragma unroll
            for (int r = 0; r < 4; ++r) {
                const int rw = mt * 16 + quad * 4 + r;
                f32x4 p0 = *(const f32x4*)&ssrow2[rw][0];
                f32x4 p4 = *(const f32x4*)&ssrow2[rw][4];
                float ss = ((p0[0] + p0[1]) + (p0[2] + p0[3])) +
                           ((p4[0] + p4[1]) + (p4[2] + p4[3]));
                float inv = 1.0f / fmaxf(sqrtf(ss), 1e-12f);
                float o = tv[mt][r] * inv;
                if (GM == 0) {
                    o = fmaxf(o, 0.f);
                    bn1 += o; bn2 += o * o;
                    float po = __shfl_xor(o, 1, 64);
                    if (!(lane & 1))
                        ((u32*)outbuf)[rw * 64 + wv * 8 + (col >> 1)] = packbf(o, po);
                } else {
                    ((float*)outbuf)[rw * 128 + wv * 16 + col] = o;
                }
            }
        ldsbar();  // out-bounce complete

        // ---- linear full-line global write ----
        const size_t rowbase = (size_t)t * 32;
        if (GM == 0) {
            u32x4 v = *(const u32x4*)(outbuf + tid * 16);
            *(u32x4*)((char*)outb + rowbase * 256 + tid * 16) = v;  // cached: rhh reused
        } else {
            f32x4 v0 = *(const f32x4*)(outbuf + tid * 32);
            f32x4 v1 = *(const f32x4*)(outbuf + tid * 32 + 16);
            ntstore(v0, (f32x4*)((char*)outf + rowbase * 512 + tid * 32));
            ntstore(v1, (f32x4*)((char*)outf + rowbase * 512 + tid * 32 + 16));
        }
        cur ^= 1;
    }

    if (GM == 0) {
        bn1 += __shfl_xor(bn1, 16, 64); bn1 += __shfl_xor(bn1, 32, 64);
        bn2 += __shfl_xor(bn2, 16, 64); bn2 += __shfl_xor(bn2, 32, 64);
        if (lane < 16) {  // quad==0 lanes hold per-feature totals
            const int slot = (blockIdx.x & 7) * 256;
            atomicAdd(&bnsums[slot + wv * 16 + lane], bn1);
            atomicAdd(&bnsums[slot + 128 + wv * 16 + lane], bn2);
        }
    }
}

// ---------------- BN finalize: scale/shift from 8-slot sums ----------------
__global__ void bnfin_kernel(const float* __restrict__ sums, const float* __restrict__ gamma,
                             const float* __restrict__ beta, float* __restrict__ bnp) {
    int f = threadIdx.x;
    if (f >= 128) return;
    float s1 = 0.f, s2 = 0.f;
#pragma unroll
    for (int k = 0; k < 8; ++k) {
        s1 += sums[k * 256 + f];
        s2 += sums[k * 256 + 128 + f];
    }
    const float invN = 1.0f / (float)N_NODES;
    float mu = s1 * invN;
    float var = s2 * invN - mu * mu;
    float sc = gamma[f] * rsqrtf(fmaxf(var, 0.f) + 1e-5f);
    bnp[f] = sc;
    bnp[128 + f] = beta[f] - mu * sc;
}

// ---------------- layer-2 weight prep: Wr2' = s .* Wr2 (split+permute), bias2' ----
__global__ void wprep_kernel(const float* __restrict__ Wr2, const float* __restrict__ bl2,
                             const float* __restrict__ bnp, u16* __restrict__ wh,
                             u16* __restrict__ wl, float* __restrict__ bias2p) {
    __shared__ float p[2];
    const int f = blockIdx.x;
    const int k = threadIdx.x;  // 128 threads
    float w = Wr2[f * 128 + k];
    float contrib = w * bnp[128 + k];
    float v = w * bnp[k];
    u16 h = f2bf(v);
    const int ks = k >> 5, quad = (k >> 3) & 3, j = k & 7;
    const int dst = ((f >> 4) * 4 + ks) * 512 + (quad * 16 + (f & 15)) * 8 + j;
    wh[dst] = h;
    wl[dst] = f2bf(v - bf2f(h));
#pragma unroll
    for (int m = 1; m <= 32; m <<= 1) contrib += __shfl_xor(contrib, m, 64);
    if ((k & 63) == 0) p[k >> 6] = contrib;
    __syncthreads();
    if (k == 0) bias2p[f] = bl2[f] + p[0] + p[1];
}

extern "C" void kernel_launch(void* const* d_in, const int* in_sizes, int n_in,
                              void* d_out, int out_size, void* d_ws, size_t ws_size,
                              hipStream_t stream) {
    const int N = N_NODES;
    const int E = in_sizes[1] / 2;
    const int nblk3 = (E + CHUNK3 - 1) / CHUNK3;

    const float* x     = (const float*)d_in[0];
    const int*   ei    = (const int*)d_in[1];
    const float* Wl1   = (const float*)d_in[2];
    const float* bl1   = (const float*)d_in[3];
    const float* Wr1   = (const float*)d_in[4];
    const float* gamma = (const float*)d_in[5];
    const float* beta  = (const float*)d_in[6];
    const float* Wl2   = (const float*)d_in[7];
    const float* bl2   = (const float*)d_in[8];
    const float* Wr2   = (const float*)d_in[9];
    float* outp = (float*)d_out;

    char* ws = (char*)d_ws;
    size_t off = 0;
    auto alloc = [&](size_t b) { size_t r = off; off += (b + 255) & ~(size_t)255; return r; };
    int*   flag     = (int*)  (ws + alloc(4));
    int*   cnt      = (int*)  (ws + alloc((size_t)N * 4));
    int*   rowstart = (int*)  (ws + alloc((size_t)(N + 1) * 4));
    int*   fill     = (int*)  (ws + alloc((size_t)N * 4));
    int*   partials = (int*)  (ws + alloc(4096));
    int*   bstart   = (int*)  (ws + alloc((NB_BKT + 1) * 4));
    int*   btot     = (int*)  (ws + alloc(NB_BKT * 4));
    int*   blkcnt   = (int*)  (ws + alloc((size_t)nblk3 * NB_BKT * 4));
    int*   qbase    = (int*)  (ws + alloc((size_t)nblk3 * NB_BKT * 4));
    int*   csr      = (int*)  (ws + alloc((size_t)E * 4));
    int*   qsrc     = (int*)  (ws + alloc((size_t)E * 4));
    int*   qdst     = (int*)  (ws + alloc((size_t)E * 4));
    float* bnsums   = (float*)(ws + alloc(2048 * 4));   // 8 slots x 256
    float* bnp      = (float*)(ws + alloc(256 * 4));
    float* bias2p   = (float*)(ws + alloc(128 * 4));
    u16*   w1c      = (u16*)  (ws + alloc(65536 * 2));  // 4 planes: lh,ll,rh,rl
    u16*   w2c      = (u16*)  (ws + alloc(65536 * 2));  // 4 planes: lh,ll,rsh,rsl
    u16*   xh       = (u16*)  (ws + alloc((size_t)N * 128 * 2));
    u16*   xl       = (u16*)  (ws + alloc((size_t)N * 128 * 2));
    u16*   meanbf   = (u16*)  (ws + alloc((size_t)N * 128 * 2));
    u16*   rhh      = (u16*)  (ws + alloc((size_t)N * 128 * 2));  // ~125 MB total

    hipMemsetAsync(bnsums, 0, 2048 * 4, stream);

    // ---- CSR build v3.1: bucket partition + hierarchical parallel scan ----------
    detect_kernel<<<1, 64, 0, stream>>>(ei, flag, E);
    eccnt3_kernel<<<nblk3, 256, 0, stream>>>(ei, blkcnt, flag, E, nblk3);
    qscanA_kernel<<<NB_BKT, 256, 0, stream>>>(blkcnt, qbase, btot, nblk3);
    qscanB_kernel<<<1, 256, 0, stream>>>(btot, bstart);
    ec3_kernel<<<nblk3, 256, 0, stream>>>(ei, qbase, bstart, qsrc, qdst, flag, E, nblk3);
    hist3_kernel<<<NB_BKT, 256, 0, stream>>>(qdst, bstart, cnt);
    const int nb = (N + 1023) / 1024;
    scan1_kernel<<<nb, 1024, 0, stream>>>(cnt, rowstart, fill, partials, N);
    scan2_kernel<<<1, 1024, 0, stream>>>(partials, nb);
    scan3_kernel<<<nb, 1024, 0, stream>>>(rowstart, fill, partials, bstart, N);
    scatter3_kernel<<<NB_BKT, 256, 0, stream>>>(qsrc, qdst, bstart, fill, csr);

    wsplitp_kernel<<<8, 256, 0, stream>>>(Wl1, w1c, w1c + 16384);
    wsplitp_kernel<<<8, 256, 0, stream>>>(Wr1, w1c + 32768, w1c + 49152);
    wsplitp_kernel<<<8, 256, 0, stream>>>(Wl2, w2c, w2c + 16384);
    xtobf_kernel<<<(N * 64 + 255) / 256, 256, 0, stream>>>(x, xh, xl, N * 64);

    // conv1
    agg_kernel<0><<<(N + 3) / 4, 256, 0, stream>>>(xh, rowstart, csr, meanbf, nullptr);
    gemm_kernel<0><<<GGRID, 512, 0, stream>>>(meanbf, xh, xl, w1c,
                                              bl1, nullptr, rhh, bnsums);
    bnfin_kernel<<<1, 128, 0, stream>>>(bnsums, gamma, beta, bnp);
    wprep_kernel<<<128, 128, 0, stream>>>(Wr2, bl2, bnp, w2c + 32768, w2c + 49152, bias2p);
    // conv2
    agg_kernel<1><<<(N + 3) / 4, 256, 0, stream>>>(rhh, rowstart, csr, meanbf, bnp);
    gemm_kernel<1><<<GGRID, 512, 0, stream>>>(meanbf, rhh, nullptr, w2c,
                                              bias2p, outp, nullptr, nullptr);
}

// Round 9
// 425.266 us; speedup vs baseline: 1.3376x; 1.0553x over previous
//
#include <hip/hip_runtime.h>

typedef unsigned short u16;
typedef unsigned int   u32;

#define N_NODES 100000
#define NB_BKT 196    // ceil(N_NODES / 512): final dst-range buckets
#define CHUNK3 8192
#define NTILES 3125   // N_NODES / 32, exact
#define GGRID  512

typedef short frag8 __attribute__((ext_vector_type(8)));
typedef float f32x4 __attribute__((ext_vector_type(4)));
typedef float f32x2 __attribute__((ext_vector_type(2)));
typedef u32   u32x4 __attribute__((ext_vector_type(4)));

template <typename T>
__device__ __forceinline__ T ntload(const T* p) { return __builtin_nontemporal_load(p); }
template <typename T>
__device__ __forceinline__ void ntstore(T v, T* p) { __builtin_nontemporal_store(v, p); }

__device__ __forceinline__ float bf2f(u16 h) {
    union { u32 u; float f; } c; c.u = ((u32)h) << 16; return c.f;
}
__device__ __forceinline__ u16 f2bf(float f) {
    union { float f; u32 u; } c; c.f = f;
    u32 u = c.u;
    return (u16)((u + 0x7FFFu + ((u >> 16) & 1u)) >> 16);
}
__device__ __forceinline__ float2 bfx2(u32 u) {
    union { u32 u; float f; } lo, hi;
    lo.u = u << 16; hi.u = u & 0xFFFF0000u;
    return make_float2(lo.f, hi.f);
}
__device__ __forceinline__ u32 packbf(float a, float b) {
    return (u32)f2bf(a) | ((u32)f2bf(b) << 16);
}
__device__ __forceinline__ void accum8(float* av, u32x4 q) {
    float2 p0 = bfx2(q[0]), p1 = bfx2(q[1]), p2 = bfx2(q[2]), p3 = bfx2(q[3]);
    av[0] += p0.x; av[1] += p0.y; av[2] += p1.x; av[3] += p1.y;
    av[4] += p2.x; av[5] += p2.y; av[6] += p3.x; av[7] += p3.y;
}

// global -> LDS direct DMA, 16B/lane, linear LDS dest (wave-uniform base + lane*16);
// global source address is PER-LANE (m104) -> fragment-ordered staging.
__device__ __forceinline__ void gload16(const void* g, void* lds) {
    __builtin_amdgcn_global_load_lds(
        (const __attribute__((address_space(1))) unsigned int*)g,
        (__attribute__((address_space(3))) unsigned int*)lds, 16, 0, 0);
}

// LDS-only barrier: orders DS ops without draining vmcnt (keeps staging in flight)
__device__ __forceinline__ void ldsbar() {
    asm volatile("s_waitcnt lgkmcnt(0)" ::: "memory");
    __builtin_amdgcn_s_barrier();
}

union U8 { frag8 f; u16 h[8]; };

// ---------------- edge-index layout detect (int32 vs int64) ----------------
__global__ void detect_kernel(const int* __restrict__ ei, int* __restrict__ flag, int E) {
    int any = 0;
    int lim = min(2048, 2 * E);
    for (int i = 1 + 2 * (int)threadIdx.x; i < lim; i += 128) any |= ei[i];
    unsigned long long b = __ballot(any != 0);
    if (threadIdx.x == 0) *flag = (b != 0ULL) ? 1 : 0;  // 1 => int32 layout
}

// ==================== CSR build v3: ZERO device-scope atomics =====================
// Edges partitioned into 196 dst-range buckets (bucket = d>>9); ONE block owns ONE
// bucket for hist and scatter -> per-edge atomics are LDS-only; cnt/csr direct.

// ---- per-(chunk,bucket) counts: LDS hist, stored g-major for linear scans --------
__global__ __launch_bounds__(256) void eccnt3_kernel(const int* __restrict__ ei,
                                                     int* __restrict__ blkcnt,
                                                     const int* __restrict__ flag,
                                                     int E, int nblk) {
    __shared__ int h[NB_BKT];
    const int tid = threadIdx.x;
    for (int i = tid; i < NB_BKT; i += 256) h[i] = 0;
    __syncthreads();
    const int is32 = *flag;
    const int base = blockIdx.x * CHUNK3;
    for (int i = tid; i < CHUNK3; i += 256) {
        int e = base + i;
        if (e < E) {
            int d = is32 ? ntload(&ei[E + e]) : ntload(&ei[2 * (E + (long long)e)]);
            if ((u32)d < (u32)N_NODES) atomicAdd(&h[d >> 9], 1);
        }
    }
    __syncthreads();
    for (int i = tid; i < NB_BKT; i += 256) blkcnt[i * nblk + blockIdx.x] = h[i];
}

// qscanA: one block per bucket scans its nblk per-chunk counts (within-bucket
// exclusive prefix -> qbase, total -> btot). All coalesced, LDS Hillis-Steele.
__global__ __launch_bounds__(256) void qscanA_kernel(const int* __restrict__ blkcnt,
                                                     int* __restrict__ qbase,
                                                     int* __restrict__ btot, int nblk) {
    __shared__ int lds[256];
    const int g = blockIdx.x;
    const int t = threadIdx.x;
    int carry = 0;
    for (int base = 0; base < nblk; base += 256) {
        const int idx = base + t;
        int v = (idx < nblk) ? blkcnt[g * nblk + idx] : 0;
        lds[t] = v;
        __syncthreads();
        for (int off = 1; off < 256; off <<= 1) {
            int x = (t >= off) ? lds[t - off] : 0;
            __syncthreads();
            lds[t] += x;
            __syncthreads();
        }
        if (idx < nblk) qbase[g * nblk + idx] = carry + lds[t] - v;  // excl prefix
        carry += lds[255];
        __syncthreads();
    }
    if (t == 0) btot[g] = carry;
}

// qscanB: single small scan of the 196 bucket totals -> bstart (exclusive).
__global__ void qscanB_kernel(const int* __restrict__ btot, int* __restrict__ bstart) {
    __shared__ int lds[256];
    const int t = threadIdx.x;
    int v = (t < NB_BKT) ? btot[t] : 0;
    lds[t] = v;
    __syncthreads();
    for (int off = 1; off < 256; off <<= 1) {
        int x = (t >= off) ? lds[t - off] : 0;
        __syncthreads();
        lds[t] += x;
        __syncthreads();
    }
    if (t < NB_BKT) bstart[t] = lds[t] - v;
    if (t == 255) bstart[NB_BKT] = lds[255];
}

// ---- partition edges into 196 dense bucket queues (LDS cursors, no ballots) ------
__global__ __launch_bounds__(256) void ec3_kernel(const int* __restrict__ ei,
                                                  const int* __restrict__ qbase,
                                                  const int* __restrict__ bstart,
                                                  int* __restrict__ qsrc,
                                                  int* __restrict__ qdst,
                                                  const int* __restrict__ flag,
                                                  int E, int nblk) {
    __shared__ int cur[NB_BKT];
    const int tid = threadIdx.x;
    for (int i = tid; i < NB_BKT; i += 256)
        cur[i] = qbase[i * nblk + blockIdx.x] + bstart[i];
    __syncthreads();
    const int is32 = *flag;
    const int base = blockIdx.x * CHUNK3;
    for (int i = tid; i < CHUNK3; i += 256) {
        int e = base + i;
        if (e < E) {
            int d = is32 ? ntload(&ei[E + e]) : ntload(&ei[2 * (E + (long long)e)]);
            if ((u32)d < (u32)N_NODES) {
                int s = is32 ? ntload(&ei[e]) : ntload(&ei[2 * (long long)e]);
                if ((u32)s >= (u32)N_NODES) s = 0;
                int p = atomicAdd(&cur[d >> 9], 1);  // LDS atomic
                qdst[p] = d;
                qsrc[p] = s;
            }
        }
    }
}

// ---- per-bucket histogram: block-exclusive, LDS bins, DIRECT cnt stores ----------
__global__ __launch_bounds__(256) void hist3_kernel(const int* __restrict__ qdst,
                                                    const int* __restrict__ bstart,
                                                    int* __restrict__ cnt) {
    __shared__ int h[512];
    const int g = blockIdx.x;
    const int tid = threadIdx.x;
    h[tid] = 0; h[tid + 256] = 0;
    __syncthreads();
    const int qs = bstart[g], qe = bstart[g + 1];
    for (int i = qs + tid; i < qe; i += 256)
        atomicAdd(&h[ntload(&qdst[i]) & 511], 1);  // LDS atomic
    __syncthreads();
    const int node0 = g << 9;
    if (node0 + tid < N_NODES) cnt[node0 + tid] = h[tid];
    if (node0 + 256 + tid < N_NODES) cnt[node0 + 256 + tid] = h[tid + 256];
}

__global__ void scan1_kernel(const int* __restrict__ cnt, int* __restrict__ row,
                             int* __restrict__ fill, int* __restrict__ part, int n) {
    __shared__ int lds[1024];
    int t = threadIdx.x, g = blockIdx.x * 1024 + t;
    int v = (g < n) ? cnt[g] : 0;
    lds[t] = v;
    __syncthreads();
    for (int off = 1; off < 1024; off <<= 1) {
        int x = (t >= off) ? lds[t - off] : 0;
        __syncthreads();
        lds[t] += x;
        __syncthreads();
    }
    if (g < n) { row[g] = lds[t] - v; fill[g] = lds[t]; }  // excl / incl (= row[g+1])
    if (t == 1023) part[blockIdx.x] = lds[t];               // block total
}

__global__ void scan2_kernel(int* __restrict__ part, int nb) {
    __shared__ int lds[1024];
    int t = threadIdx.x;
    int v = (t < nb) ? part[t] : 0;
    lds[t] = v;
    __syncthreads();
    for (int off = 1; off < 1024; off <<= 1) {
        int x = (t >= off) ? lds[t - off] : 0;
        __syncthreads();
        lds[t] += x;
        __syncthreads();
    }
    if (t < nb) part[t] = lds[t] - v;
}

__global__ void scan3_kernel(int* __restrict__ row, int* __restrict__ fill,
                             const int* __restrict__ part,
                             const int* __restrict__ bstart, int n) {
    int g = blockIdx.x * 1024 + threadIdx.x;
    if (g < n) { int p = part[blockIdx.x]; row[g] += p; fill[g] += p; }
    if (g == 0) row[n] = bstart[NB_BKT];
}

// ---- per-bucket scatter: LDS cursors from fill slice, LDS atomicSub, direct csr --
__global__ __launch_bounds__(256) void scatter3_kernel(const int* __restrict__ qsrc,
                                                       const int* __restrict__ qdst,
                                                       const int* __restrict__ bstart,
                                                       const int* __restrict__ fill,
                                                       int* __restrict__ csr) {
    __shared__ int cur[512];
    const int g = blockIdx.x;
    const int tid = threadIdx.x;
    const int node0 = g << 9;
    if (node0 + tid < N_NODES) cur[tid] = fill[node0 + tid];
    if (node0 + 256 + tid < N_NODES) cur[tid + 256] = fill[node0 + 256 + tid];
    __syncthreads();
    const int qs = bstart[g], qe = bstart[g + 1];
    for (int i = qs + tid; i < qe; i += 256) {
        int d = ntload(&qdst[i]);
        int s = ntload(&qsrc[i]);
        int idx = atomicSub(&cur[d & 511], 1) - 1;  // LDS atomic
        csr[idx] = s;  // block-exclusive ~33KB range: L2-resident, evicted once
    }
}

// ---------------- weight split+permute: W(fp32) -> bf16 hi/lo planes, MFMA-frag ----
// fragment-contiguous layout: frag (ks,ft) for lane l at (ft*4+ks)*512 + l*8.
__global__ void wsplitp_kernel(const float* __restrict__ W, u16* __restrict__ hi,
                               u16* __restrict__ lo) {
    int t = blockIdx.x * 256 + threadIdx.x;  // 2048 threads: f x (ks,quad)
    if (t >= 2048) return;
    const int f = t >> 4, ks = (t >> 2) & 3, quad = t & 3;
    const int dst = ((f >> 4) * 4 + ks) * 512 + (quad * 16 + (f & 15)) * 8;
    const float* src = W + f * 128 + ks * 32 + quad * 8;
    U8 h, l;
#pragma unroll
    for (int j = 0; j < 8; ++j) {
        float v = src[j];
        u16 hh = f2bf(v);
        h.h[j] = hh;
        l.h[j] = f2bf(v - bf2f(hh));
    }
    *(frag8*)(hi + dst) = h.f;
    *(frag8*)(lo + dst) = l.f;
}

// ---------------- x -> bf16 hi + lo planes (hi: agg gather + gemm; lo: gemm) -------
__global__ void xtobf_kernel(const float* __restrict__ X, u16* __restrict__ outh,
                             u16* __restrict__ outl, int n2) {
    int i = blockIdx.x * 256 + threadIdx.x;
    if (i >= n2) return;
    f32x2 v = ntload(&((const f32x2*)X)[i]);
    u16 h0 = f2bf(v[0]), h1 = f2bf(v[1]);
    ((u32*)outh)[i] = (u32)h0 | ((u32)h1 << 16);
    ((u32*)outl)[i] = (u32)f2bf(v[0] - bf2f(h0)) | ((u32)f2bf(v[1] - bf2f(h1)) << 16);
}

// ---------------- mean aggregation over CSR (bf16 rows -> bf16 mean) ----------------
template <int MODE>
__global__ __launch_bounds__(256) void agg_kernel(
    const u16* __restrict__ X, const int* __restrict__ rowstart,
    const int* __restrict__ csr, u16* __restrict__ out,
    const float* __restrict__ bnp) {
    const int wid = (blockIdx.x * 256 + threadIdx.x) >> 6;
    const int lane = threadIdx.x & 63;
    const int g = lane >> 4;
    const int l = lane & 15;
    if (wid >= N_NODES) return;
    const int s = rowstart[wid];
    const int deg = rowstart[wid + 1] - s;
    const u32x4* Xv = (const u32x4*)X;  // row = 16 u32x4
    float av[8] = {0.f, 0.f, 0.f, 0.f, 0.f, 0.f, 0.f, 0.f};
    for (int base = 0; base < deg; base += 64) {
        const int nb = min(deg - base, 64);
        const int myidx = csr[s + base + min(lane, nb - 1)];  // one coalesced load
        int c = 0;
#pragma unroll 4
        for (; c + 4 <= nb; c += 4) {
            const int idx = __shfl(myidx, c + g, 64);
            u32x4 q = Xv[(size_t)idx * 16 + l];
            accum8(av, q);
        }
        if (c < nb) {  // tail: 1..3 neighbors
            const int idx = __shfl(myidx, min(c + g, nb - 1), 64);
            u32x4 q = Xv[(size_t)idx * 16 + l];
            if (c + g < nb) accum8(av, q);
        }
    }
#pragma unroll
    for (int j = 0; j < 8; ++j) {
        av[j] += __shfl_xor(av[j], 16, 64);
        av[j] += __shfl_xor(av[j], 32, 64);
    }
    if (g == 0) {
        const float inv = 1.0f / (float)max(deg, 1);
#pragma unroll
        for (int j = 0; j < 8; ++j) av[j] *= inv;
        if (MODE == 1) {
            if (deg > 0) {
#pragma unroll
                for (int j = 0; j < 8; ++j)
                    av[j] = av[j] * bnp[l * 8 + j] + bnp[128 + l * 8 + j];
            } else {
#pragma unroll
                for (int j = 0; j < 8; ++j) av[j] = 0.f;
            }
        }
        u32x4 o;
        o[0] = packbf(av[0], av[1]); o[1] = packbf(av[2], av[3]);
        o[2] = packbf(av[4], av[5]); o[3] = packbf(av[6], av[7]);
        ((u32x4*)out)[(size_t)wid * 16 + l] = o;  // cached: consumed by gemm
    }
}

// ---------------- fused GEMM v7: spill-proofed, 128-reg budget, 2 blocks/CU --------
// R8 post-mortem: VGPR_Count=64 (R5's spill fingerprint) + VALUBusy 34% + ~19MB
// extra WRITE => compiler software-pipelined the t-loop (cur^=1 invited unroll x2)
// and spilled past budget. v7: launch_bounds(512,4)=128-reg budget (2 blocks/CU
// guaranteed if fit; live estimate ~115), #pragma unroll 1 on t-loop, explicit
// pointer swap, loop-invariant staging voffset, NO outbuf bounce (direct paired
// cached stores; rows complete in L2 -> full-line evictions), 2 barriers/tile.
template <int GM>
__global__ __launch_bounds__(512, 4) void gemm_kernel(
    const u16* __restrict__ A1bf, const u16* __restrict__ A2h_,
    const u16* __restrict__ A2l_, const u16* __restrict__ Wc,
    const float* __restrict__ bias, float* __restrict__ outf,
    u16* __restrict__ outb, float* __restrict__ bnsums) {
    constexpr int NREG = (GM == 0) ? 3 : 2;  // staging regions (A1,A2h[,A2l])
    constexpr int TB = NREG * 8192;          // bytes per buffer
    __shared__ __align__(16) char bufA[TB], bufB[TB];
    __shared__ float ssrow2[32][8];  // [row][wave] L2-norm partials
    const int tid = threadIdx.x;
    const int lane = tid & 63;
    const int wv = tid >> 6;      // 0..7 = output-feature slice AND staging chunk id
    const int col = lane & 15;
    const int quad = lane >> 4;

    // loop-invariant per-lane staging offset: chunk c=wv covers rows (c>>2)*16+col,
    // k-bytes (c&3)*64 + quad*16 (full 64B lines per row)
    const int voff = (((wv >> 2) << 4) + col) * 256 + ((wv & 3) << 6) + (quad << 4);

    auto stage = [&](char* buf, int trow0) {
        const size_t b = (size_t)trow0 * 256 + voff;
        gload16((const char*)A1bf + b, buf + wv * 1024);
        gload16((const char*)A2h_ + b, buf + 8192 + wv * 1024);
        if (GM == 0) gload16((const char*)A2l_ + b, buf + 16384 + wv * 1024);
    };

    // ---- weights: this wave's ft slice, all planes/ksteps, register-resident ----
    char* cbuf = bufA;
    char* nbuf = bufB;
    stage(cbuf, blockIdx.x * 32);
    frag8 wlh[4], wll[4], wrh[4], wrl[4];
#pragma unroll
    for (int ks = 0; ks < 4; ++ks) {
        const int wo = (wv * 4 + ks) * 512 + lane * 8;
        wlh[ks] = *(const frag8*)(Wc + wo);
        wll[ks] = *(const frag8*)(Wc + 16384 + wo);
        wrh[ks] = *(const frag8*)(Wc + 32768 + wo);
        wrl[ks] = *(const frag8*)(Wc + 49152 + wo);
    }
    const float bsv = bias[wv * 16 + col];
    float bn1 = 0.f, bn2 = 0.f;

#pragma unroll 1
    for (int t = blockIdx.x; t < NTILES; t += GGRID) {
        __syncthreads();  // drains vmcnt: cbuf staged; prev-tile ssrow2 reads done
        if (t + GGRID < NTILES) stage(nbuf, (t + GGRID) * 32);

        // ---- k-loop: lane-contiguous LDS fragment reads + MFMA, zero VALU ----
        f32x4 acc0 = (f32x4){0.f, 0.f, 0.f, 0.f};
        f32x4 acc1 = (f32x4){0.f, 0.f, 0.f, 0.f};
#pragma unroll
        for (int ks = 0; ks < 4; ++ks) {
            const int fo = ks * 1024 + lane * 16;
            frag8 a10 = *(const frag8*)(cbuf + fo);
            frag8 a11 = *(const frag8*)(cbuf + 4096 + fo);
            frag8 h0 = *(const frag8*)(cbuf + 8192 + fo);
            frag8 h1 = *(const frag8*)(cbuf + 12288 + fo);
            acc0 = __builtin_amdgcn_mfma_f32_16x16x32_bf16(a10, wlh[ks], acc0, 0, 0, 0);
            acc0 = __builtin_amdgcn_mfma_f32_16x16x32_bf16(a10, wll[ks], acc0, 0, 0, 0);
            acc0 = __builtin_amdgcn_mfma_f32_16x16x32_bf16(h0, wrh[ks], acc0, 0, 0, 0);
            acc0 = __builtin_amdgcn_mfma_f32_16x16x32_bf16(h0, wrl[ks], acc0, 0, 0, 0);
            acc1 = __builtin_amdgcn_mfma_f32_16x16x32_bf16(a11, wlh[ks], acc1, 0, 0, 0);
            acc1 = __builtin_amdgcn_mfma_f32_16x16x32_bf16(a11, wll[ks], acc1, 0, 0, 0);
            acc1 = __builtin_amdgcn_mfma_f32_16x16x32_bf16(h1, wrh[ks], acc1, 0, 0, 0);
            acc1 = __builtin_amdgcn_mfma_f32_16x16x32_bf16(h1, wrl[ks], acc1, 0, 0, 0);
            if (GM == 0) {
                frag8 l0 = *(const frag8*)(cbuf + 16384 + fo);
                frag8 l1 = *(const frag8*)(cbuf + 20480 + fo);
                acc0 = __builtin_amdgcn_mfma_f32_16x16x32_bf16(l0, wrh[ks], acc0, 0, 0, 0);
                acc1 = __builtin_amdgcn_mfma_f32_16x16x32_bf16(l1, wrh[ks], acc1, 0, 0, 0);
            }
        }

        // ---- epilogue: bias, cross-wave row-norm, direct paired stores ----
        float sq0[4], sq1[4];
#pragma unroll
        for (int r = 0; r < 4; ++r) {
            acc0[r] += bsv; acc1[r] += bsv;
            sq0[r] = acc0[r] * acc0[r];
            sq1[r] = acc1[r] * acc1[r];
        }
#pragma unroll
        for (int m = 1; m <= 8; m <<= 1)
#pragma unroll
            for (int r = 0; r < 4; ++r) {
                sq0[r] += __shfl_xor(sq0[r], m, 64);
                sq1[r] += __shfl_xor(sq1[r], m, 64);
            }
        if (col == 0) {
#pragma unroll
            for (int r = 0; r < 4; ++r) {
                ssrow2[quad * 4 + r][wv] = sq0[r];
                ssrow2[16 + quad * 4 + r][wv] = sq1[r];
            }
        }
        ldsbar();  // partials visible; staging stays in flight

        const size_t row0 = (size_t)t * 32;
#pragma unroll
        for (int mt = 0; mt < 2; ++mt)
#pragma unroll
            for (int r = 0; r < 4; ++r) {
                const int rw = mt * 16 + quad * 4 + r;
                f32x4 p0 = *(const f32x4*)&ssrow2[rw][0];
                f32x4 p4 = *(const f32x4*)&ssrow2[rw][4];
                float ss = ((p0[0] + p0[1]) + (p0[2] + p0[3])) +
                           ((p4[0] + p4[1]) + (p4[2] + p4[3]));
                float inv = 1.0f / fmaxf(sqrtf(ss), 1e-12f);
                float o = (mt == 0 ? acc0[r] : acc1[r]) * inv;
                if (GM == 0) {
                    o = fmaxf(o, 0.f);
                    bn1 += o; bn2 += o * o;
                }
                float po = __shfl_xor(o, 1, 64);
                if (!(lane & 1)) {
                    const size_t ridx = (row0 + rw) * 64 + wv * 8 + (col >> 1);
                    if (GM == 0) {
                        ((u32*)outb)[ridx] = packbf(o, po);  // cached: rhh reused
                    } else {
                        f32x2 o2; o2[0] = o; o2[1] = po;
                        ((f32x2*)outf)[ridx] = o2;  // cached: full lines form in L2
                    }
                }
            }
        char* tmp = cbuf; cbuf = nbuf; nbuf = tmp;
    }

    if (GM == 0) {
        bn1 += __shfl_xor(bn1, 16, 64); bn1 += __shfl_xor(bn1, 32, 64);
        bn2 += __shfl_xor(bn2, 16, 64); bn2 += __shfl_xor(bn2, 32, 64);
        if (lane < 16) {  // quad==0 lanes hold per-feature totals
            const int slot = (blockIdx.x & 63) * 256;
            atomicAdd(&bnsums[slot + wv * 16 + lane], bn1);
            atomicAdd(&bnsums[slot + 128 + wv * 16 + lane], bn2);
        }
    }
}

// ---------------- BN finalize: scale/shift from 64-slot sums ----------------
__global__ void bnfin_kernel(const float* __restrict__ sums, const float* __restrict__ gamma,
                             const float* __restrict__ beta, float* __restrict__ bnp) {
    int f = threadIdx.x;
    if (f >= 128) return;
    float s1 = 0.f, s2 = 0.f;
#pragma unroll
    for (int k = 0; k < 64; ++k) {
        s1 += sums[k * 256 + f];
        s2 += sums[k * 256 + 128 + f];
    }
    const float invN = 1.0f / (float)N_NODES;
    float mu = s1 * invN;
    float var = s2 * invN - mu * mu;
    float sc = gamma[f] * rsqrtf(fmaxf(var, 0.f) + 1e-5f);
    bnp[f] = sc;
    bnp[128 + f] = beta[f] - mu * sc;
}

// ---------------- layer-2 weight prep: Wr2' = s .* Wr2 (split+permute), bias2' ----
__global__ void wprep_kernel(const float* __restrict__ Wr2, const float* __restrict__ bl2,
                             const float* __restrict__ bnp, u16* __restrict__ wh,
                             u16* __restrict__ wl, float* __restrict__ bias2p) {
    __shared__ float p[2];
    const int f = blockIdx.x;
    const int k = threadIdx.x;  // 128 threads
    float w = Wr2[f * 128 + k];
    float contrib = w * bnp[128 + k];
    float v = w * bnp[k];
    u16 h = f2bf(v);
    const int ks = k >> 5, quad = (k >> 3) & 3, j = k & 7;
    const int dst = ((f >> 4) * 4 + ks) * 512 + (quad * 16 + (f & 15)) * 8 + j;
    wh[dst] = h;
    wl[dst] = f2bf(v - bf2f(h));
#pragma unroll
    for (int m = 1; m <= 32; m <<= 1) contrib += __shfl_xor(contrib, m, 64);
    if ((k & 63) == 0) p[k >> 6] = contrib;
    __syncthreads();
    if (k == 0) bias2p[f] = bl2[f] + p[0] + p[1];
}

extern "C" void kernel_launch(void* const* d_in, const int* in_sizes, int n_in,
                              void* d_out, int out_size, void* d_ws, size_t ws_size,
                              hipStream_t stream) {
    const int N = N_NODES;
    const int E = in_sizes[1] / 2;
    const int nblk3 = (E + CHUNK3 - 1) / CHUNK3;

    const float* x     = (const float*)d_in[0];
    const int*   ei    = (const int*)d_in[1];
    const float* Wl1   = (const float*)d_in[2];
    const float* bl1   = (const float*)d_in[3];
    const float* Wr1   = (const float*)d_in[4];
    const float* gamma = (const float*)d_in[5];
    const float* beta  = (const float*)d_in[6];
    const float* Wl2   = (const float*)d_in[7];
    const float* bl2   = (const float*)d_in[8];
    const float* Wr2   = (const float*)d_in[9];
    float* outp = (float*)d_out;

    char* ws = (char*)d_ws;
    size_t off = 0;
    auto alloc = [&](size_t b) { size_t r = off; off += (b + 255) & ~(size_t)255; return r; };
    int*   flag     = (int*)  (ws + alloc(4));
    int*   cnt      = (int*)  (ws + alloc((size_t)N * 4));
    int*   rowstart = (int*)  (ws + alloc((size_t)(N + 1) * 4));
    int*   fill     = (int*)  (ws + alloc((size_t)N * 4));
    int*   partials = (int*)  (ws + alloc(4096));
    int*   bstart   = (int*)  (ws + alloc((NB_BKT + 1) * 4));
    int*   btot     = (int*)  (ws + alloc(NB_BKT * 4));
    int*   blkcnt   = (int*)  (ws + alloc((size_t)nblk3 * NB_BKT * 4));
    int*   qbase    = (int*)  (ws + alloc((size_t)nblk3 * NB_BKT * 4));
    int*   csr      = (int*)  (ws + alloc((size_t)E * 4));
    int*   qsrc     = (int*)  (ws + alloc((size_t)E * 4));
    int*   qdst     = (int*)  (ws + alloc((size_t)E * 4));
    float* bnsums   = (float*)(ws + alloc(64 * 256 * 4));  // 64 slots x 256
    float* bnp      = (float*)(ws + alloc(256 * 4));
    float* bias2p   = (float*)(ws + alloc(128 * 4));
    u16*   w1c      = (u16*)  (ws + alloc(65536 * 2));  // 4 planes: lh,ll,rh,rl
    u16*   w2c      = (u16*)  (ws + alloc(65536 * 2));  // 4 planes: lh,ll,rsh,rsl
    u16*   xh       = (u16*)  (ws + alloc((size_t)N * 128 * 2));
    u16*   xl       = (u16*)  (ws + alloc((size_t)N * 128 * 2));
    u16*   meanbf   = (u16*)  (ws + alloc((size_t)N * 128 * 2));
    u16*   rhh      = (u16*)  (ws + alloc((size_t)N * 128 * 2));  // ~125 MB total

    hipMemsetAsync(bnsums, 0, 64 * 256 * 4, stream);

    // ---- CSR build v3.1: bucket partition + hierarchical parallel scan ----------
    detect_kernel<<<1, 64, 0, stream>>>(ei, flag, E);
    eccnt3_kernel<<<nblk3, 256, 0, stream>>>(ei, blkcnt, flag, E, nblk3);
    qscanA_kernel<<<NB_BKT, 256, 0, stream>>>(blkcnt, qbase, btot, nblk3);
    qscanB_kernel<<<1, 256, 0, stream>>>(btot, bstart);
    ec3_kernel<<<nblk3, 256, 0, stream>>>(ei, qbase, bstart, qsrc, qdst, flag, E, nblk3);
    hist3_kernel<<<NB_BKT, 256, 0, stream>>>(qdst, bstart, cnt);
    const int nb = (N + 1023) / 1024;
    scan1_kernel<<<nb, 1024, 0, stream>>>(cnt, rowstart, fill, partials, N);
    scan2_kernel<<<1, 1024, 0, stream>>>(partials, nb);
    scan3_kernel<<<nb, 1024, 0, stream>>>(rowstart, fill, partials, bstart, N);
    scatter3_kernel<<<NB_BKT, 256, 0, stream>>>(qsrc, qdst, bstart, fill, csr);

    wsplitp_kernel<<<8, 256, 0, stream>>>(Wl1, w1c, w1c + 16384);
    wsplitp_kernel<<<8, 256, 0, stream>>>(Wr1, w1c + 32768, w1c + 49152);
    wsplitp_kernel<<<8, 256, 0, stream>>>(Wl2, w2c, w2c + 16384);
    xtobf_kernel<<<(N * 64 + 255) / 256, 256, 0, stream>>>(x, xh, xl, N * 64);

    // conv1
    agg_kernel<0><<<(N + 3) / 4, 256, 0, stream>>>(xh, rowstart, csr, meanbf, nullptr);
    gemm_kernel<0><<<GGRID, 512, 0, stream>>>(meanbf, xh, xl, w1c,
                                              bl1, nullptr, rhh, bnsums);
    bnfin_kernel<<<1, 128, 0, stream>>>(bnsums, gamma, beta, bnp);
    wprep_kernel<<<128, 128, 0, stream>>>(Wr2, bl2, bnp, w2c + 32768, w2c + 49152, bias2p);
    // conv2
    agg_kernel<1><<<(N + 3) / 4, 256, 0, stream>>>(rhh, rowstart, csr, meanbf, bnp);
    gemm_kernel<1><<<GGRID, 512, 0, stream>>>(meanbf, rhh, nullptr, w2c,
                                              bias2p, outp, nullptr, nullptr);
}